// Round 15
// baseline (233.183 us; speedup 1.0000x reference)
//
#include <hip/hip_runtime.h>

typedef unsigned short u16;
typedef unsigned int u32;
typedef __bf16 bf16x8 __attribute__((ext_vector_type(8)));
typedef short s16x4 __attribute__((ext_vector_type(4)));
typedef float f32x4 __attribute__((ext_vector_type(4)));

#define NEG_INF -3.0e38f
#define QSCALE 0.18033688011f   // 0.125 * log2(e): softmax done in exp2 domain

__device__ __forceinline__ u16 f2bf(float f){
  union { float f; u32 u; } v; v.f = f;
  u32 r = v.u + 0x7fffu + ((v.u >> 16) & 1u);
  return (u16)(r >> 16);
}
__device__ __forceinline__ float bf2f(u16 h){
  union { u32 u; float f; } v; v.u = ((u32)h) << 16; return v.f;
}
__device__ __forceinline__ short f2bf_s(float f){
  union { __bf16 h; short s; } cv; cv.h = (__bf16)f; return cv.s;
}

__device__ __forceinline__ f32x4 mfma16(s16x4 a, s16x4 b, f32x4 c){
#if __has_builtin(__builtin_amdgcn_mfma_f32_16x16x16bf16_1k)
  return __builtin_amdgcn_mfma_f32_16x16x16bf16_1k(a, b, c, 0, 0, 0);
#else
  asm("v_mfma_f32_16x16x16_bf16 %0, %1, %2, %0" : "+v"(c) : "v"(a), "v"(b));
  return c;
#endif
}

__device__ __forceinline__ void gl_lds16(const void* g, void* l){
  __builtin_amdgcn_global_load_lds((const __attribute__((address_space(1))) void*)g,
      (__attribute__((address_space(3))) void*)l, 16, 0, 0);
}

// ---------------- LayerNorm rows of 512, fp32 in -> bf16 out ----------------
__device__ __forceinline__ void ln_body(const float* __restrict__ xr,
    const float* __restrict__ g, const float* __restrict__ b,
    u16* __restrict__ orow, int lane){
  float4 v0 = *(const float4*)(xr + lane * 4);
  float4 v1 = *(const float4*)(xr + 256 + lane * 4);
  float s = v0.x+v0.y+v0.z+v0.w + v1.x+v1.y+v1.z+v1.w;
  float q = v0.x*v0.x+v0.y*v0.y+v0.z*v0.z+v0.w*v0.w
          + v1.x*v1.x+v1.y*v1.y+v1.z*v1.z+v1.w*v1.w;
  #pragma unroll
  for (int d=1; d<64; d<<=1){ s += __shfl_xor(s, d, 64); q += __shfl_xor(q, d, 64); }
  float mean = s * (1.0f/512.0f);
  float var  = q * (1.0f/512.0f) - mean*mean;
  float rs = rsqrtf(var + 1e-5f);
  float4 g0 = *(const float4*)(g + lane*4), g1 = *(const float4*)(g + 256 + lane*4);
  float4 b0 = *(const float4*)(b + lane*4), b1 = *(const float4*)(b + 256 + lane*4);
  uint2 pa, pb;
  pa.x = (u32)f2bf((v0.x-mean)*rs*g0.x + b0.x) | ((u32)f2bf((v0.y-mean)*rs*g0.y + b0.y) << 16);
  pa.y = (u32)f2bf((v0.z-mean)*rs*g0.z + b0.z) | ((u32)f2bf((v0.w-mean)*rs*g0.w + b0.w) << 16);
  pb.x = (u32)f2bf((v1.x-mean)*rs*g1.x + b1.x) | ((u32)f2bf((v1.y-mean)*rs*g1.y + b1.y) << 16);
  pb.y = (u32)f2bf((v1.z-mean)*rs*g1.z + b1.z) | ((u32)f2bf((v1.w-mean)*rs*g1.w + b1.w) << 16);
  *(uint2*)(orow + lane*4) = pa;
  *(uint2*)(orow + 256 + lane*4) = pb;
}

__global__ __launch_bounds__(256) void ln_rows(const float* __restrict__ x,
    const float* __restrict__ g, const float* __restrict__ b,
    u16* __restrict__ out, int rows){
  int wid = threadIdx.x >> 6, lane = threadIdx.x & 63;
  int row = blockIdx.x * 4 + wid;
  if (row >= rows) return;
  ln_body(x + (size_t)row*512, g, b, out + (size_t)row*512, lane);
}

// ---------------- fused prep: 7 weight transposes + LN(q) + LN(kv) + mask ---
struct WtJobs {
  const float* W[7]; u16* Wt[7];
  int K[7], Nfull[7], ncol0[7], nt[7], blk0[7];
};
struct PrepArgs {
  WtJobs wt; int totW;
  const float *x0, *g0, *b0; u16* o0; int nb0, rows0;
  const float *x1, *g1, *b1; u16* o1; int nb1, rows1;
  const int* mask; u32* mw;
};

__global__ __launch_bounds__(256) void prep_all(PrepArgs P){
  __shared__ float tile[32][33];
  __shared__ unsigned long long blds[4];
  int bb = blockIdx.x;
  int tid = threadIdx.x;
  int wid = tid >> 6, lane = tid & 63;
  if (bb < P.totW){
    const WtJobs& J = P.wt;
    const float* W = J.W[0]; u16* Wt = J.Wt[0];
    int K = J.K[0], Nfull = J.Nfull[0], ncol0 = J.ncol0[0], nt = J.nt[0], blk0 = 0;
    #pragma unroll
    for (int i=1;i<7;i++)
      if (bb >= J.blk0[i]){
        W=J.W[i]; Wt=J.Wt[i]; K=J.K[i]; Nfull=J.Nfull[i]; ncol0=J.ncol0[i]; nt=J.nt[i]; blk0=J.blk0[i];
      }
    int lb = bb - blk0;
    int tk = lb / nt, tn = lb % nt;
    int col = tid & 31, kr = tid >> 5;
    #pragma unroll
    for (int i=0;i<4;i++){
      int k = tk*32 + kr + i*8;
      tile[kr + i*8][col] = W[(size_t)k*Nfull + ncol0 + tn*32 + col];
    }
    __syncthreads();
    int nl = tid >> 3, kc = (tid & 7) * 4;
    uint2 o;
    o.x = (u32)f2bf(tile[kc+0][nl]) | ((u32)f2bf(tile[kc+1][nl]) << 16);
    o.y = (u32)f2bf(tile[kc+2][nl]) | ((u32)f2bf(tile[kc+3][nl]) << 16);
    *(uint2*)(Wt + (size_t)(tn*32 + nl)*K + tk*32 + kc) = o;
  } else if (bb < P.totW + P.nb0){
    int row = (bb - P.totW)*4 + wid;
    if (row >= P.rows0) return;
    ln_body(P.x0 + (size_t)row*512, P.g0, P.b0, P.o0 + (size_t)row*512, lane);
  } else if (bb < P.totW + P.nb0 + P.nb1){
    int row = (bb - P.totW - P.nb0)*4 + wid;
    if (row >= P.rows1) return;
    ln_body(P.x1 + (size_t)row*512, P.g1, P.b1, P.o1 + (size_t)row*512, lane);
  } else {
    int lb = bb - P.totW - P.nb0 - P.nb1;
    int r0 = lb*2 + (wid >> 1);
    int word = tid & 127;
    const int* mr = P.mask + (size_t)r0*4096 + word*32;
    u32 w = 0;
    #pragma unroll
    for (int j=0;j<32;j+=4){
      int4 v = *(const int4*)(mr + j);
      w |= (u32)(v.x!=0) << j;
      w |= (u32)(v.y!=0) << (j+1);
      w |= (u32)(v.z!=0) << (j+2);
      w |= (u32)(v.w!=0) << (j+3);
    }
    blds[wid] = __ballot(w != 0);
    __syncthreads();
    bool any = (wid < 2) ? ((blds[0] | blds[1]) != 0ull) : ((blds[2] | blds[3]) != 0ull);
    P.mw[(size_t)r0*128 + word] = any ? w : 0xffffffffu;
  }
}

// ---------------- GEMM: C[M,N] = A[M,K] * Bt[N,K]^T, bf16 MFMA -------------
// Multi-job dispatch (2 jobs/launch), geometry runtime, EPILOGUE COMPILE-TIME.
// epi 0 = bf16 (+QSCALE cols<scale_cols), 1 = bf16+ReLU, 2 = fp32+residual,
// 3 = KV split, 4 = bf16 + row bias, 5 = fp32 split-K partial.
struct GemmJob {
  const u16* A; const u16* Bt; const float* bias;
  float* outf; u16* outb; const float* res; u16* out2;
  int M, N, K, lda, k0, ksplit, scale_cols, T1, rows_per_b, vstride, swz, brmap, blk0, nblk;
};
struct GemmJobs { GemmJob j[2]; int njobs; };

template<int EPI>
__device__ __forceinline__ void epi_store(const GemmJob& J, f32x4 (&acc)[4][4],
    int m0, int n0, int wm, int wn, int lg, int l15, int ksp){
  if (EPI == 3){
    float bv[4];
    #pragma unroll
    for (int ni=0;ni<4;ni++) bv[ni] = J.bias[n0 + wn*64 + ni*16 + l15];
    #pragma unroll
    for (int ni=0;ni<4;ni++){
      int c = n0 + wn*64 + ni*16 + l15;
      #pragma unroll
      for (int mi=0;mi<4;mi++){
        int mr0 = m0 + wm*64 + mi*16 + lg*4;
        if (mr0 >= J.M) continue;
        if (c < J.T1){
          #pragma unroll
          for (int r4=0;r4<4;r4++)
            J.outb[(size_t)(mr0+r4)*J.T1 + c] = f2bf(acc[mi][ni][r4] + bv[ni]);
        } else {
          int bidx = mr0 / J.rows_per_b;
          int key  = mr0 - bidx*J.rows_per_b;
          uint2 o;
          o.x = (u32)f2bf(acc[mi][ni][0]+bv[ni]) | ((u32)f2bf(acc[mi][ni][1]+bv[ni])<<16);
          o.y = (u32)f2bf(acc[mi][ni][2]+bv[ni]) | ((u32)f2bf(acc[mi][ni][3]+bv[ni])<<16);
          *(uint2*)(J.out2 + ((size_t)bidx*512 + (c - J.T1))*J.vstride + key) = o;
        }
      }
    }
  } else if (EPI == 4){
    #pragma unroll
    for (int mi=0;mi<4;mi++){
      #pragma unroll
      for (int r4=0;r4<4;r4++){
        int m = m0 + wm*64 + mi*16 + lg*4 + r4;
        if (m >= J.M) continue;
        float rb = J.bias[m];
        #pragma unroll
        for (int ni=0;ni<4;ni++){
          int c = n0 + wn*64 + ni*16 + l15;
          J.outb[(size_t)m*J.N + c] = f2bf(acc[mi][ni][r4] + rb);
        }
      }
    }
  } else if (EPI == 5){
    float* po_ = J.outf + (size_t)ksp*J.M*J.N;
    #pragma unroll
    for (int mi=0;mi<4;mi++){
      #pragma unroll
      for (int r4=0;r4<4;r4++){
        int m = m0 + wm*64 + mi*16 + lg*4 + r4;
        if (m >= J.M) continue;
        #pragma unroll
        for (int ni=0;ni<4;ni++){
          int c = n0 + wn*64 + ni*16 + l15;
          po_[(size_t)m*J.N + c] = acc[mi][ni][r4];
        }
      }
    }
  } else {
    float bv[4], scl[4];
    #pragma unroll
    for (int ni=0;ni<4;ni++){
      int c = n0 + wn*64 + ni*16 + l15;
      bv[ni]  = J.bias[c];
      scl[ni] = (c < J.scale_cols) ? QSCALE : 1.0f;
    }
    #pragma unroll
    for (int mi=0;mi<4;mi++){
      #pragma unroll
      for (int r4=0;r4<4;r4++){
        int m = m0 + wm*64 + mi*16 + lg*4 + r4;
        if (m >= J.M) continue;
        #pragma unroll
        for (int ni=0;ni<4;ni++){
          int c = n0 + wn*64 + ni*16 + l15;
          float v = acc[mi][ni][r4] + bv[ni];
          if (EPI == 0){
            J.outb[(size_t)m*J.N + c] = f2bf(v*scl[ni]);
          } else if (EPI == 1){
            J.outb[(size_t)m*J.N + c] = f2bf(fmaxf(v, 0.0f));
          } else {
            J.outf[(size_t)m*J.N + c] = v + J.res[(size_t)m*J.N + c];
          }
        }
      }
    }
  }
}

template<int EPI>
__device__ __forceinline__ void gemm_block(const GemmJob& J, int bidIn, u16* As, u16* Bs){
  int bid = bidIn;
  int ksp = 0;
  if (J.ksplit > 1){ ksp = bid / J.nblk; bid = bid % J.nblk; }
  if (J.swz){ int cpx = J.nblk >> 3; bid = (bid & 7)*cpx + (bid >> 3); }
  int NT = J.N >> 7;
  int mt = bid / NT, nt = bid % NT;
  int m0 = mt << 7, n0 = nt << 7;
  int kofs = J.k0 + ksp * J.K;
  int tid = threadIdx.x;
  int wid = tid >> 6, lane = tid & 63;
  int wm = wid >> 1, wn = wid & 1;
  int lg = lane >> 4, l15 = lane & 15;

  f32x4 acc[4][4] = {};
  int ktiles = J.K >> 6;
  for (int kt = 0; kt < ktiles; ++kt){
    int k0 = kofs + (kt << 6);
    if (kt) __syncthreads();
    #pragma unroll
    for (int i=0;i<4;i++){
      int L = i*4096 + tid*16;
      int T = L ^ (((L>>7)&7)<<4);
      int row = T >> 7, colb = T & 127;
      int ga = m0 + row; if (ga > J.M-1) ga = J.M-1;
      gl_lds16((const char*)J.A + ((size_t)ga*J.lda + k0)*2 + colb, (char*)As + L);
    }
    #pragma unroll
    for (int i=0;i<4;i++){
      int L = i*4096 + tid*16;
      int T = L ^ (((L>>7)&7)<<4);
      int row = T >> 7, colb = T & 127;
      int rowg = n0 + row;
      if (J.brmap){ int rb = rowg & 127; rowg = (rowg>>7)*J.brmap + (rb < J.brmap ? rb : J.brmap-1); }
      gl_lds16((const char*)J.Bt + ((size_t)rowg*J.lda + k0)*2 + colb, (char*)Bs + L);
    }
    __syncthreads();
    #pragma unroll
    for (int ks=0; ks<2; ++ks){
      bf16x8 af[4], bfr[4];
      #pragma unroll
      for (int mi=0; mi<4; ++mi){
        int r = wm*64 + mi*16 + l15;
        int byt = r*128 + ks*64 + lg*16;
        af[mi] = *(const bf16x8*)((const char*)As + (byt ^ ((r&7)<<4)));
      }
      #pragma unroll
      for (int ni=0; ni<4; ++ni){
        int r = wn*64 + ni*16 + l15;
        int byt = r*128 + ks*64 + lg*16;
        bfr[ni] = *(const bf16x8*)((const char*)Bs + (byt ^ ((r&7)<<4)));
      }
      __builtin_amdgcn_s_setprio(1);
      #pragma unroll
      for (int mi=0;mi<4;mi++)
        #pragma unroll
        for (int ni=0;ni<4;ni++)
          acc[mi][ni] = __builtin_amdgcn_mfma_f32_16x16x32_bf16(af[mi], bfr[ni], acc[mi][ni], 0,0,0);
      __builtin_amdgcn_s_setprio(0);
    }
  }
  epi_store<EPI>(J, acc, m0, n0, wm, wn, lg, l15, ksp);
}

template<int EPIA, int EPIB>
__global__ __launch_bounds__(256) void gemm_multi(GemmJobs G){
  __shared__ __align__(16) u16 As[8192];
  __shared__ __align__(16) u16 Bs[8192];
  bool second = (G.njobs > 1) && ((int)blockIdx.x >= G.j[1].blk0);
  if (second) gemm_block<EPIB>(G.j[1], (int)blockIdx.x - G.j[1].blk0, As, Bs);
  else        gemm_block<EPIA>(G.j[0], (int)blockIdx.x, As, Bs);
}

// ---------------- 256x256-tile GEMM, 8 waves, k-split phases, counted vmcnt -
// K=512 fixed (KT=8 tiles of BK=64, each 2 k-halves of 32). LDS 128KB:
// A,B tiles [2 buf][2 kh][256 rows][32 k] bf16, 16B slot s stored at
// s^(row&3) (pre-swizzled global source, linear LDS dest). Per phase (one
// k-half): stage next tile's (A,B) pair for this half (4 gl_lds16/thread),
// s_waitcnt vmcnt(8) (never 0 mid-loop), raw s_barrier, 12 ds_read_b128,
// 32 MFMA, s_barrier. epi 0 = bf16*QSCALE (Q proj), 3 = KV split.
struct G256Job {
  const u16* A; const u16* Bt; const float* bias;
  u16* outb; u16* out2;
  int M, N, lda, epi, nblk, swz;
};

__global__ __launch_bounds__(512, 2) void gemm256(G256Job J0, G256Job J1, int blk1, int njobs){
  __shared__ __align__(16) char lds[131072];
  G256Job J = J0;
  int lb = blockIdx.x;
  if (njobs > 1 && lb >= blk1){ J = J1; lb -= blk1; }
  if (J.swz){ int cpx = J.nblk >> 3; lb = (lb & 7)*cpx + (lb >> 3); }
  int NT = J.N >> 8;
  int mt = lb / NT, nt = lb % NT;
  int m0 = mt << 8, n0 = nt << 8;
  int tid = threadIdx.x;
  int wid = tid >> 6, lane = tid & 63;
  int wm = wid >> 2, wn = wid & 3;
  int lg = lane >> 4, l15 = lane & 15;
  const int KT = 8;
  char* Al = lds;
  char* Bl = lds + 65536;

  auto stage_pair = [&](int t, int h){
    int bufo = ((t & 1) << 15) | (h << 14);
    #pragma unroll
    for (int i=0;i<2;i++){
      int idx = i*512 + tid;
      int row = idx >> 2, s = idx & 3;
      int sg = s ^ (row & 3);
      int ga = m0 + row; if (ga > J.M-1) ga = J.M-1;
      gl_lds16((const char*)J.A + ((size_t)ga*J.lda + t*64 + h*32 + sg*8)*2,
               Al + bufo + idx*16);
    }
    #pragma unroll
    for (int i=0;i<2;i++){
      int idx = i*512 + tid;
      int row = idx >> 2, s = idx & 3;
      int sg = s ^ (row & 3);
      gl_lds16((const char*)J.Bt + ((size_t)(n0 + row)*J.lda + t*64 + h*32 + sg*8)*2,
               Bl + bufo + idx*16);
    }
  };

  f32x4 acc[8][4] = {};
  stage_pair(0, 0);
  stage_pair(0, 1);
  for (int t=0; t<KT; ++t){
    #pragma unroll
    for (int h=0; h<2; ++h){
      if (t+1 < KT){
        stage_pair(t+1, h);
        asm volatile("s_waitcnt vmcnt(8)" ::: "memory");
      } else if (h == 0){
        asm volatile("s_waitcnt vmcnt(4)" ::: "memory");
      } else {
        asm volatile("s_waitcnt vmcnt(0)" ::: "memory");
      }
      __builtin_amdgcn_s_barrier();
      int bufo = ((t & 1) << 15) | (h << 14);
      bf16x8 af[8], bfr[4];
      #pragma unroll
      for (int ni=0;ni<4;ni++){
        int row = wn*64 + ni*16 + l15;
        bfr[ni] = *(const bf16x8*)(Bl + bufo + row*64 + ((lg ^ (row&3))<<4));
      }
      #pragma unroll
      for (int mi=0;mi<8;mi++){
        int row = wm*128 + mi*16 + l15;
        af[mi] = *(const bf16x8*)(Al + bufo + row*64 + ((lg ^ (row&3))<<4));
      }
      __builtin_amdgcn_s_setprio(1);
      #pragma unroll
      for (int mi=0;mi<8;mi++)
        #pragma unroll
        for (int ni=0;ni<4;ni++)
          acc[mi][ni] = __builtin_amdgcn_mfma_f32_16x16x32_bf16(af[mi], bfr[ni], acc[mi][ni], 0,0,0);
      __builtin_amdgcn_s_setprio(0);
      __builtin_amdgcn_s_barrier();
    }
  }

  float bv[4];
  #pragma unroll
  for (int ni=0;ni<4;ni++) bv[ni] = J.bias[n0 + wn*64 + ni*16 + l15];
  if (J.epi == 0){
    #pragma unroll
    for (int mi=0;mi<8;mi++){
      #pragma unroll
      for (int r=0;r<4;r++){
        int m = m0 + wm*128 + mi*16 + lg*4 + r;
        if (m >= J.M) continue;
        #pragma unroll
        for (int ni=0;ni<4;ni++){
          int c = n0 + wn*64 + ni*16 + l15;
          J.outb[(size_t)m*J.N + c] = f2bf((acc[mi][ni][r] + bv[ni])*QSCALE);
        }
      }
    }
  } else if (n0 < 512){
    // K half -> kp row-major [M][512]
    #pragma unroll
    for (int mi=0;mi<8;mi++){
      #pragma unroll
      for (int r=0;r<4;r++){
        int m = m0 + wm*128 + mi*16 + lg*4 + r;
        #pragma unroll
        for (int ni=0;ni<4;ni++){
          int c = n0 + wn*64 + ni*16 + l15;
          J.outb[(size_t)m*512 + c] = f2bf(acc[mi][ni][r] + bv[ni]);
        }
      }
    }
  } else {
    // V half -> vpT[(bidx*512 + f)*4096 + key]
    #pragma unroll
    for (int ni=0;ni<4;ni++){
      int f = n0 - 512 + wn*64 + ni*16 + l15;
      #pragma unroll
      for (int mi=0;mi<8;mi++){
        int m = m0 + wm*128 + mi*16 + lg*4;
        int bidx = m >> 12, key = m & 4095;
        uint2 o;
        o.x = (u32)f2bf(acc[mi][ni][0]+bv[ni]) | ((u32)f2bf(acc[mi][ni][1]+bv[ni])<<16);
        o.y = (u32)f2bf(acc[mi][ni][2]+bv[ni]) | ((u32)f2bf(acc[mi][ni][3]+bv[ni])<<16);
        *(uint2*)(J.out2 + ((size_t)bidx*512 + f)*4096 + key) = o;
      }
    }
  }
}

// split-K reduce: out = res + bias[c] + sum_s part[s]; 4 floats per thread
__global__ __launch_bounds__(256) void splitk_reduce(
    const float* __restrict__ part, int nsplit, const float* __restrict__ bias,
    const float* __restrict__ res, float* __restrict__ out, int N, int total4)
{
  int idx = (blockIdx.x*256 + threadIdx.x);
  if (idx >= total4) return;
  int e0 = idx*4;
  size_t MN = (size_t)total4*4;
  float4 a = *(const float4*)(part + e0);
  #pragma unroll
  for (int s=1;s<4;s++){
    float4 p = *(const float4*)(part + s*MN + e0);
    a.x += p.x; a.y += p.y; a.z += p.z; a.w += p.w;
  }
  float4 r = *(const float4*)(res + e0);
  int c = e0 & (N-1);
  float4 bv = *(const float4*)(bias + c);
  float4 o;
  o.x = a.x + r.x + bv.x; o.y = a.y + r.y + bv.y;
  o.z = a.z + r.z + bv.z; o.w = a.w + r.w + bv.w;
  *(float4*)(out + e0) = o;
}

// ---------------- flash attention: 64-key tiles, 2-buf counted-vmcnt pipe ---
template<bool PARTIAL, bool HASMASK, int NTILES>
__global__ __launch_bounds__(256) void attn_kernel(
    const u16* __restrict__ Qp, int ldq,
    const u16* __restrict__ Kp, int ldk, int kcol0,
    const u16* __restrict__ VT, size_t vbs, int vfs,
    const u32* __restrict__ maskw,
    float* __restrict__ pm, float* __restrict__ pl, u16* __restrict__ po,
    u16* __restrict__ o_out,
    int nq, int mk, int S, int H, int Bp, int swz)
{
  __shared__ __align__(16) u16 Ks[2*4096];
  __shared__ __align__(16) u16 Vs[2*4096];
  int bid = blockIdx.x;
  if (swz){ int cpx = gridDim.x >> 3; bid = (bid & 7)*cpx + (bid >> 3); }
  int s = bid % S; int h = (bid / S) % H; int b = bid / (S*H);
  int tid = threadIdx.x, wid = tid>>6, lane = tid&63;
  int lg = lane>>4, l15 = lane&15;
  int qbase = b*nq;
  int kps = mk / S;
  int kbeg = s * kps;
  int mwld = mk >> 5;
  int krel = lg*4;

  bf16x8 qf[2][2];
  #pragma unroll
  for (int mt=0;mt<2;mt++){
    int qr = wid*32 + mt*16 + l15; int qc = qr < nq ? qr : nq-1;
    #pragma unroll
    for (int ks=0;ks<2;ks++)
      qf[mt][ks] = *(const bf16x8*)(Qp + (size_t)(qbase+qc)*ldq + h*64 + ks*32 + lg*8);
  }
  u32 wmw[2][2*NTILES];
  if (HASMASK){
    #pragma unroll
    for (int mt=0;mt<2;mt++){
      int qc = (wid*32 + mt*16 + l15) < nq ? (wid*32 + mt*16 + l15) : nq-1;
      const u32* mrow = maskw + (size_t)(qbase+qc)*mwld + (kbeg>>5);
      #pragma unroll
      for (int wi=0; wi<2*NTILES; wi+=4){
        uint4 v = *(const uint4*)(mrow + wi);
        wmw[mt][wi+0]=v.x; wmw[mt][wi+1]=v.y; wmw[mt][wi+2]=v.z; wmw[mt][wi+3]=v.w;
      }
    }
  }

  float m_r[2] = {NEG_INF, NEG_INF};
  float l_r[2] = {0.0f, 0.0f};
  f32x4 of[2][4] = {};

  auto stage = [&](int t_, int bufi){
    int kb_ = kbeg + t_*64;
    #pragma unroll
    for (int i=0;i<2;i++){
      int idx = i*256 + tid;
      int key = idx>>3, sd = idx&7;
      int kc = kb_ + key; if (kc > mk-1) kc = mk-1;
      const char* src = (const char*)(Kp + (size_t)(b*mk + kc)*ldk + kcol0 + h*64) + ((sd ^ (key&7))<<4);
      gl_lds16(src, (char*)Ks + bufi*8192 + idx*16);
    }
    #pragma unroll
    for (int i=0;i<2;i++){
      int idx = i*256 + tid;
      int f = idx>>3, sd = idx&7;
      const char* src = (const char*)(VT + (size_t)b*vbs + (size_t)(h*64+f)*vfs + kb_) + ((sd ^ (f&7))<<4);
      gl_lds16(src, (char*)Vs + bufi*8192 + idx*16);
    }
  };

  stage(0, 0);

  #pragma unroll
  for (int t=0;t<NTILES;t++){
    if (t+1 < NTILES){
      stage(t+1, (t+1)&1);
      asm volatile("s_waitcnt vmcnt(4)" ::: "memory");
    } else {
      asm volatile("s_waitcnt vmcnt(0)" ::: "memory");
    }
    __builtin_amdgcn_s_barrier();

    const char* Kb = (const char*)Ks + (t&1)*8192;
    const char* Vb = (const char*)Vs + (t&1)*8192;
    int kb = kbeg + t*64;

    f32x4 sT[4][2] = {};
    #pragma unroll
    for (int nt2=0;nt2<4;nt2++){
      bf16x8 k0 = *(const bf16x8*)(Kb + ((nt2*16+l15)<<7) + (((lg  ) ^ (l15&7))<<4));
      bf16x8 k1 = *(const bf16x8*)(Kb + ((nt2*16+l15)<<7) + (((4+lg) ^ (l15&7))<<4));
      __builtin_amdgcn_s_setprio(1);
      #pragma unroll
      for (int mt=0;mt<2;mt++){
        sT[nt2][mt] = __builtin_amdgcn_mfma_f32_16x16x32_bf16(k0, qf[mt][0], sT[nt2][mt], 0,0,0);
        sT[nt2][mt] = __builtin_amdgcn_mfma_f32_16x16x32_bf16(k1, qf[mt][1], sT[nt2][mt], 0,0,0);
      }
      __builtin_amdgcn_s_setprio(0);
    }

    s16x4 pb[2][4];
    #pragma unroll
    for (int mt=0;mt<2;mt++){
      float mx = NEG_INF;
      #pragma unroll
      for (int nt2=0;nt2<4;nt2++){
        u32 wb = 0;
        if (HASMASK) wb = wmw[mt][t*2 + (nt2>>1)] >> (((nt2&1)<<4) + krel);
        #pragma unroll
        for (int r=0;r<4;r++){
          bool ok = HASMASK ? (((wb>>r)&1u) != 0) : (kb + nt2*16 + krel + r < mk);
          float sv = ok ? sT[nt2][mt][r] : NEG_INF;
          sT[nt2][mt][r] = sv;
          mx = fmaxf(mx, sv);
        }
      }
      mx = fmaxf(mx, __shfl_xor(mx, 16, 64));
      mx = fmaxf(mx, __shfl_xor(mx, 32, 64));
      if (!__all(mx <= m_r[mt] + 8.0f)){
        float mnew = fmaxf(m_r[mt], mx);
        float corr = exp2f(m_r[mt] - mnew);
        m_r[mt] = mnew;
        l_r[mt] *= corr;
        #pragma unroll
        for (int nf=0;nf<4;nf++) of[mt][nf] *= corr;
      }
      float ps = 0.0f;
      #pragma unroll
      for (int nt2=0;nt2<4;nt2++)
        #pragma unroll
        for (int r=0;r<4;r++){
          float p = exp2f(sT[nt2][mt][r] - m_r[mt]);
          ps += p;
          pb[mt][nt2][r] = f2bf_s(p);
        }
      ps += __shfl_xor(ps, 16, 64);
      ps += __shfl_xor(ps, 32, 64);
      l_r[mt] += ps;
    }

    #pragma unroll
    for (int nf=0;nf<4;nf++){
      s16x4 vf[4];
      #pragma unroll
      for (int nt2=0;nt2<4;nt2++){
        int slot = (nt2*2 + (lg>>1)) ^ (l15&7);
        vf[nt2] = *(const s16x4*)(Vb + ((nf*16+l15)<<7) + (slot<<4) + ((lg&1)<<3));
      }
      __builtin_amdgcn_s_setprio(1);
      #pragma unroll
      for (int mt=0;mt<2;mt++)
        #pragma unroll
        for (int nt2=0;nt2<4;nt2++)
          of[mt][nf] = mfma16(vf[nt2], pb[mt][nt2], of[mt][nf]);
      __builtin_amdgcn_s_setprio(0);
    }
    __builtin_amdgcn_s_barrier();
  }

  #pragma unroll
  for (int mt=0;mt<2;mt++){
    int q = wid*32 + mt*16 + l15;
    if (q < nq){
      if (PARTIAL){
        size_t base = (((size_t)(s*Bp + b)*H + h)*128 + q);
        if (lg == 0){ pm[base] = m_r[mt]; pl[base] = l_r[mt]; }
        #pragma unroll
        for (int nf=0;nf<4;nf++){
          uint2 o;
          o.x = (u32)f2bf(of[mt][nf][0]) | ((u32)f2bf(of[mt][nf][1])<<16);
          o.y = (u32)f2bf(of[mt][nf][2]) | ((u32)f2bf(of[mt][nf][3])<<16);
          *(uint2*)(po + base*64 + nf*16 + lg*4) = o;
        }
      } else {
        float inv = 1.0f / l_r[mt];
        #pragma unroll
        for (int nf=0;nf<4;nf++){
          uint2 o;
          o.x = (u32)f2bf(of[mt][nf][0]*inv) | ((u32)f2bf(of[mt][nf][1]*inv)<<16);
          o.y = (u32)f2bf(of[mt][nf][2]*inv) | ((u32)f2bf(of[mt][nf][3]*inv)<<16);
          *(uint2*)(o_out + (size_t)(qbase+q)*512 + h*64 + nf*16 + lg*4) = o;
        }
      }
    }
  }
}

__global__ __launch_bounds__(64) void attn_combine(
    const float* __restrict__ pm, const float* __restrict__ pl, const u16* __restrict__ po,
    u16* __restrict__ o_out, int S, int Bp, int H, int nq)
{
  int bid = blockIdx.x;
  int q = bid % nq; int h = (bid / nq) % H; int b = bid / (nq*H);
  int f = threadIdx.x;
  float mstar = NEG_INF;
  for (int s=0;s<S;s++){
    size_t idx = (((size_t)(s*Bp + b)*H + h)*128 + q);
    mstar = fmaxf(mstar, pm[idx]);
  }
  float L = 0.0f, acc = 0.0f;
  for (int s=0;s<S;s++){
    size_t idx = (((size_t)(s*Bp + b)*H + h)*128 + q);
    float w = exp2f(pm[idx] - mstar);
    L += w * pl[idx];
    acc += w * bf2f(po[idx*64 + f]);
  }
  o_out[((size_t)b*nq + q)*512 + h*64 + f] = f2bf(acc / L);
}

// ---------------------------------------------------------------------------
extern "C" void kernel_launch(void* const* d_in, const int* in_sizes, int n_in,
                              void* d_out, int out_size, void* d_ws, size_t ws_size,
                              hipStream_t stream){
  const float* q_in    = (const float*)d_in[0];
  const float* kv_in   = (const float*)d_in[1];
  const int*   maskb   = (const int*)d_in[2];
  const float* xa_Wqkv = (const float*)d_in[3];
  const float* xa_bqkv = (const float*)d_in[4];
  const float* xa_Wo   = (const float*)d_in[5];
  const float* xa_bo   = (const float*)d_in[6];
  const float* xa_gq   = (const float*)d_in[7];
  const float* xa_bq   = (const float*)d_in[8];
  const float* xa_gkv  = (const float*)d_in[9];
  const float* xa_bkv  = (const float*)d_in[10];
  const float* sa_Wqkv = (const float*)d_in[11];
  const float* sa_bqkv = (const float*)d_in[12];
  const float* sa_Wo   = (const float*)d_in[13];
  const float* sa_bo   = (const float*)d_in[14];
  const float* n1_g = (const float*)d_in[15];
  const float* n1_b = (const float*)d_in[16];
  const float* n2_g = (const float*)d_in[17];
  const float* n2_b = (const float*)d_in[18];
  const float* ff_W1 = (const float*)d_in[19];
  const float* ff_b1 = (const float*)d_in[20];
  const float* ff_W2 = (const float*)d_in[21];
  const float* ff_b2 = (const float*)d_in[22];

  char* ws = (char*)d_ws;
  size_t off = 0;
  auto alloc = [&](size_t bytes)->char*{ char* p = ws + off; off = (off + bytes + 255) & ~(size_t)255; return p; };
  u16* wq  = (u16*)alloc((size_t)512*512*2);
  u16* wkv = (u16*)alloc((size_t)1024*512*2);
  u16* wsa = (u16*)alloc((size_t)1536*512*2);
  u16* wxo = (u16*)alloc((size_t)512*512*2);
  u16* wso = (u16*)alloc((size_t)512*512*2);
  u16* wf1 = (u16*)alloc((size_t)2048*512*2);
  u16* wf2 = (u16*)alloc((size_t)512*2048*2);
  u16* qn  = (u16*)alloc((size_t)800*512*2);
  u16* qp  = (u16*)alloc((size_t)800*512*2);
  u32* mw  = (u32*)alloc((size_t)800*128*4);
  u16* kp  = (u16*)alloc((size_t)32768*512*2);
  u16* vpT = (u16*)alloc((size_t)8*512*4096*2);   // [(b*512+f)][4096 keys]
  size_t reuse_off = off;
  u16* kvn = (u16*)alloc((size_t)32768*512*2);
  size_t offB = reuse_off;
  auto allocB = [&](size_t bytes)->char*{ char* p = ws + offB; offB = (offB + bytes + 255) & ~(size_t)255; return p; };
  const int S = 16;
  float* pm   = (float*)allocB((size_t)S*64*128*4);
  float* pl   = (float*)allocB((size_t)S*64*128*4);
  u16*   po   = (u16*)allocB((size_t)S*64*128*64*2);
  u16* o_xa   = (u16*)allocB((size_t)800*512*2);
  float* x1   = (float*)allocB((size_t)800*512*4);
  u16* qn1    = (u16*)allocB((size_t)800*512*2);
  u16* saqkv  = (u16*)allocB((size_t)800*1024*2);
  u16* vT2sa  = (u16*)allocB((size_t)512*1024*2);
  u16* o_sa   = (u16*)allocB((size_t)800*512*2);
  float* x2   = (float*)allocB((size_t)800*512*4);
  u16* qn2    = (u16*)allocB((size_t)800*512*2);
  u16* hbuf   = (u16*)allocB((size_t)800*2048*2);
  // split-K partials (FFN2): 4 x 800x512 fp32; alias dead pm/pl/po region
  float* fpart = pm;

  // ---- single prep dispatch: 7 wtrans jobs + LN(q) + LN(kv) + mask --------
  PrepArgs P;
  P.wt.W[0]=xa_Wqkv; P.wt.Wt[0]=wq;  P.wt.K[0]=512;  P.wt.Nfull[0]=1536; P.wt.ncol0[0]=0;   P.wt.nt[0]=16;
  P.wt.W[1]=xa_Wqkv; P.wt.Wt[1]=wkv; P.wt.K[1]=512;  P.wt.Nfull[1]=1536; P.wt.ncol0[1]=512; P.wt.nt[1]=32;
  P.wt.W[2]=sa_Wqkv; P.wt.Wt[2]=wsa; P.wt.K[2]=512;  P.wt.Nfull[2]=1536; P.wt.ncol0[2]=0;   P.wt.nt[2]=48;
  P.wt.W[3]=xa_Wo;   P.wt.Wt[3]=wxo; P.wt.K[3]=512;  P.wt.Nfull[3]=512;  P.wt.ncol0[3]=0;   P.wt.nt[3]=16;
  P.wt.W[4]=sa_Wo;   P.wt.Wt[4]=wso; P.wt.K[4]=512;  P.wt.Nfull[4]=512;  P.wt.ncol0[4]=0;   P.wt.nt[4]=16;
  P.wt.W[5]=ff_W1;   P.wt.Wt[5]=wf1; P.wt.K[5]=512;  P.wt.Nfull[5]=2048; P.wt.ncol0[5]=0;   P.wt.nt[5]=64;
  P.wt.W[6]=ff_W2;   P.wt.Wt[6]=wf2; P.wt.K[6]=2048; P.wt.Nfull[6]=512;  P.wt.ncol0[6]=0;   P.wt.nt[6]=16;
  int tot = 0;
  for (int i=0;i<7;i++){ P.wt.blk0[i] = tot; tot += (P.wt.K[i]/32)*P.wt.nt[i]; }
  P.totW = tot;
  P.x0=q_in;  P.g0=xa_gq;  P.b0=xa_bq;  P.o0=qn;  P.nb0=200;  P.rows0=800;
  P.x1=kv_in; P.g1=xa_gkv; P.b1=xa_bkv; P.o1=kvn; P.nb1=8192; P.rows1=32768;
  P.mask=maskb; P.mw=mw;
  prep_all<<<tot + 200 + 8192 + 400, 256, 0, stream>>>(P);

  auto mkjob = [&](const u16*A, const u16*Bt, const float*bias, float*outf, u16*outb,
                   const float*res, u16*out2, int M, int N, int K, int lda, int k0,
                   int ksplit, int sc, int T1, int rpb, int vst, int swz, int brm,
                   int blk0, int nblk)->GemmJob{
    GemmJob j; j.A=A; j.Bt=Bt; j.bias=bias; j.outf=outf; j.outb=outb; j.res=res; j.out2=out2;
    j.M=M; j.N=N; j.K=K; j.lda=lda; j.k0=k0; j.ksplit=ksplit; j.scale_cols=sc; j.T1=T1;
    j.rows_per_b=rpb; j.vstride=vst; j.swz=swz; j.brmap=brm; j.blk0=blk0; j.nblk=nblk;
    return j;
  };

  // ---- 256^2 phased GEMM: KV projection (512 blk) || Q projection (8 blk) --
  {
    G256Job jkv, jq;
    jkv.A = kvn; jkv.Bt = wkv; jkv.bias = xa_bqkv+512; jkv.outb = kp; jkv.out2 = vpT;
    jkv.M = 32768; jkv.N = 1024; jkv.lda = 512; jkv.epi = 3; jkv.nblk = 512; jkv.swz = 1;
    jq.A = qn; jq.Bt = wq; jq.bias = xa_bqkv; jq.outb = qp; jq.out2 = nullptr;
    jq.M = 800; jq.N = 512; jq.lda = 512; jq.epi = 0; jq.nblk = 8; jq.swz = 0;
    gemm256<<<512 + 8, 512, 0, stream>>>(jkv, jq, 512, 2);
  }
  attn_kernel<true,true,4><<<8*8*S, 256, 0, stream>>>(
      qp, 512, kp, 512, 0, vpT, (size_t)512*4096, 4096, mw,
      pm, pl, po, nullptr, 100, 4096, S, 8, 8, 1);
  attn_combine<<<8*8*100, 64, 0, stream>>>(pm, pl, po, o_xa, S, 8, 8, 100);
  {
    GemmJobs g;
    g.j[0] = mkjob(o_xa, wxo, xa_bo, x1, nullptr, q_in, nullptr,
                   800, 512, 512, 512, 0, 1, 0, 0,1,1, 0,0, 0, 28);
    g.j[1] = g.j[0]; g.njobs = 1;
    gemm_multi<2,2><<<28, 256, 0, stream>>>(g);
  }
  ln_rows<<<200, 256, 0, stream>>>(x1, n1_g, n1_b, qn1, 800);
  {
    GemmJobs g;
    g.j[0] = mkjob(qn1, wsa, sa_bqkv, nullptr, saqkv, nullptr, nullptr,
                   800, 1024, 512, 512, 0, 1, 512, 0,1,1, 0,0, 0, 56);
    g.j[1] = mkjob(wsa + (size_t)1024*512, qn1, sa_bqkv+1024, nullptr, vT2sa, nullptr, nullptr,
                   512, 1024, 512, 512, 0, 1, 0, 0,1,1, 0, 100, 56, 32);
    g.njobs = 2;
    gemm_multi<0,4><<<56 + 32, 256, 0, stream>>>(g);
  }
  attn_kernel<false,false,2><<<64, 256, 0, stream>>>(
      saqkv, 1024, saqkv, 1024, 512, vT2sa, (size_t)128, 1024, nullptr,
      nullptr, nullptr, nullptr, o_sa, 100, 100, 1, 8, 8, 0);
  {
    GemmJobs g;
    g.j[0] = mkjob(o_sa, wso, sa_bo, x2, nullptr, x1, nullptr,
                   800, 512, 512, 512, 0, 1, 0, 0,1,1, 0,0, 0, 28);
    g.j[1] = g.j[0]; g.njobs = 1;
    gemm_multi<2,2><<<28, 256, 0, stream>>>(g);
  }
  ln_rows<<<200, 256, 0, stream>>>(x2, n2_g, n2_b, qn2, 800);
  {
    GemmJobs g;
    g.j[0] = mkjob(qn2, wf1, ff_b1, nullptr, hbuf, nullptr, nullptr,
                   800, 2048, 512, 512, 0, 1, 0, 0,1,1, 0,0, 0, 112);
    g.j[1] = g.j[0]; g.njobs = 1;
    gemm_multi<1,1><<<112, 256, 0, stream>>>(g);
  }
  // FFN2: split-K x4 (K=2048 -> 4x512), fp32 partials into dead attn scratch
  {
    GemmJobs g;
    g.j[0] = mkjob(hbuf, wf2, nullptr, fpart, nullptr, nullptr, nullptr,
                   800, 512, 512, 2048, 0, 4, 0, 0,1,1, 0,0, 0, 28);
    g.j[1] = g.j[0]; g.njobs = 1;
    gemm_multi<5,5><<<112, 256, 0, stream>>>(g);
  }
  splitk_reduce<<<(800*512/4 + 255)/256, 256, 0, stream>>>(
      fpart, 4, ff_b2, x2, (float*)d_out, 512, 800*512/4);
}

// Round 16
// 231.858 us; speedup vs baseline: 1.0057x; 1.0057x over previous
//
#include <hip/hip_runtime.h>

typedef unsigned short u16;
typedef unsigned int u32;
typedef __bf16 bf16x8 __attribute__((ext_vector_type(8)));
typedef short s16x4 __attribute__((ext_vector_type(4)));
typedef float f32x4 __attribute__((ext_vector_type(4)));

#define NEG_INF -3.0e38f
#define QSCALE 0.18033688011f   // 0.125 * log2(e): softmax done in exp2 domain

__device__ __forceinline__ u16 f2bf(float f){
  union { float f; u32 u; } v; v.f = f;
  u32 r = v.u + 0x7fffu + ((v.u >> 16) & 1u);
  return (u16)(r >> 16);
}
__device__ __forceinline__ float bf2f(u16 h){
  union { u32 u; float f; } v; v.u = ((u32)h) << 16; return v.f;
}
__device__ __forceinline__ short f2bf_s(float f){
  union { __bf16 h; short s; } cv; cv.h = (__bf16)f; return cv.s;
}

__device__ __forceinline__ f32x4 mfma16(s16x4 a, s16x4 b, f32x4 c){
#if __has_builtin(__builtin_amdgcn_mfma_f32_16x16x16bf16_1k)
  return __builtin_amdgcn_mfma_f32_16x16x16bf16_1k(a, b, c, 0, 0, 0);
#else
  asm("v_mfma_f32_16x16x16_bf16 %0, %1, %2, %0" : "+v"(c) : "v"(a), "v"(b));
  return c;
#endif
}

__device__ __forceinline__ void gl_lds16(const void* g, void* l){
  __builtin_amdgcn_global_load_lds((const __attribute__((address_space(1))) void*)g,
      (__attribute__((address_space(3))) void*)l, 16, 0, 0);
}

// ---------------- LayerNorm rows of 512, fp32 in -> bf16 out ----------------
__device__ __forceinline__ void ln_body(const float* __restrict__ xr,
    const float* __restrict__ g, const float* __restrict__ b,
    u16* __restrict__ orow, int lane){
  float4 v0 = *(const float4*)(xr + lane * 4);
  float4 v1 = *(const float4*)(xr + 256 + lane * 4);
  float s = v0.x+v0.y+v0.z+v0.w + v1.x+v1.y+v1.z+v1.w;
  float q = v0.x*v0.x+v0.y*v0.y+v0.z*v0.z+v0.w*v0.w
          + v1.x*v1.x+v1.y*v1.y+v1.z*v1.z+v1.w*v1.w;
  #pragma unroll
  for (int d=1; d<64; d<<=1){ s += __shfl_xor(s, d, 64); q += __shfl_xor(q, d, 64); }
  float mean = s * (1.0f/512.0f);
  float var  = q * (1.0f/512.0f) - mean*mean;
  float rs = rsqrtf(var + 1e-5f);
  float4 g0 = *(const float4*)(g + lane*4), g1 = *(const float4*)(g + 256 + lane*4);
  float4 b0 = *(const float4*)(b + lane*4), b1 = *(const float4*)(b + 256 + lane*4);
  uint2 pa, pb;
  pa.x = (u32)f2bf((v0.x-mean)*rs*g0.x + b0.x) | ((u32)f2bf((v0.y-mean)*rs*g0.y + b0.y) << 16);
  pa.y = (u32)f2bf((v0.z-mean)*rs*g0.z + b0.z) | ((u32)f2bf((v0.w-mean)*rs*g0.w + b0.w) << 16);
  pb.x = (u32)f2bf((v1.x-mean)*rs*g1.x + b1.x) | ((u32)f2bf((v1.y-mean)*rs*g1.y + b1.y) << 16);
  pb.y = (u32)f2bf((v1.z-mean)*rs*g1.z + b1.z) | ((u32)f2bf((v1.w-mean)*rs*g1.w + b1.w) << 16);
  *(uint2*)(orow + lane*4) = pa;
  *(uint2*)(orow + 256 + lane*4) = pb;
}

__global__ __launch_bounds__(256) void ln_rows(const float* __restrict__ x,
    const float* __restrict__ g, const float* __restrict__ b,
    u16* __restrict__ out, int rows){
  int wid = threadIdx.x >> 6, lane = threadIdx.x & 63;
  int row = blockIdx.x * 4 + wid;
  if (row >= rows) return;
  ln_body(x + (size_t)row*512, g, b, out + (size_t)row*512, lane);
}

// ---------------- fused prep: 7 weight transposes + LN(q) + LN(kv) + mask ---
struct WtJobs {
  const float* W[7]; u16* Wt[7];
  int K[7], Nfull[7], ncol0[7], nt[7], blk0[7];
};
struct PrepArgs {
  WtJobs wt; int totW;
  const float *x0, *g0, *b0; u16* o0; int nb0, rows0;
  const float *x1, *g1, *b1; u16* o1; int nb1, rows1;
  const int* mask; u32* mw;
};

__global__ __launch_bounds__(256) void prep_all(PrepArgs P){
  __shared__ float tile[32][33];
  __shared__ unsigned long long blds[4];
  int bb = blockIdx.x;
  int tid = threadIdx.x;
  int wid = tid >> 6, lane = tid & 63;
  if (bb < P.totW){
    const WtJobs& J = P.wt;
    const float* W = J.W[0]; u16* Wt = J.Wt[0];
    int K = J.K[0], Nfull = J.Nfull[0], ncol0 = J.ncol0[0], nt = J.nt[0], blk0 = 0;
    #pragma unroll
    for (int i=1;i<7;i++)
      if (bb >= J.blk0[i]){
        W=J.W[i]; Wt=J.Wt[i]; K=J.K[i]; Nfull=J.Nfull[i]; ncol0=J.ncol0[i]; nt=J.nt[i]; blk0=J.blk0[i];
      }
    int lb = bb - blk0;
    int tk = lb / nt, tn = lb % nt;
    int col = tid & 31, kr = tid >> 5;
    #pragma unroll
    for (int i=0;i<4;i++){
      int k = tk*32 + kr + i*8;
      tile[kr + i*8][col] = W[(size_t)k*Nfull + ncol0 + tn*32 + col];
    }
    __syncthreads();
    int nl = tid >> 3, kc = (tid & 7) * 4;
    uint2 o;
    o.x = (u32)f2bf(tile[kc+0][nl]) | ((u32)f2bf(tile[kc+1][nl]) << 16);
    o.y = (u32)f2bf(tile[kc+2][nl]) | ((u32)f2bf(tile[kc+3][nl]) << 16);
    *(uint2*)(Wt + (size_t)(tn*32 + nl)*K + tk*32 + kc) = o;
  } else if (bb < P.totW + P.nb0){
    int row = (bb - P.totW)*4 + wid;
    if (row >= P.rows0) return;
    ln_body(P.x0 + (size_t)row*512, P.g0, P.b0, P.o0 + (size_t)row*512, lane);
  } else if (bb < P.totW + P.nb0 + P.nb1){
    int row = (bb - P.totW - P.nb0)*4 + wid;
    if (row >= P.rows1) return;
    ln_body(P.x1 + (size_t)row*512, P.g1, P.b1, P.o1 + (size_t)row*512, lane);
  } else {
    int lb = bb - P.totW - P.nb0 - P.nb1;
    int r0 = lb*2 + (wid >> 1);
    int word = tid & 127;
    const int* mr = P.mask + (size_t)r0*4096 + word*32;
    u32 w = 0;
    #pragma unroll
    for (int j=0;j<32;j+=4){
      int4 v = *(const int4*)(mr + j);
      w |= (u32)(v.x!=0) << j;
      w |= (u32)(v.y!=0) << (j+1);
      w |= (u32)(v.z!=0) << (j+2);
      w |= (u32)(v.w!=0) << (j+3);
    }
    blds[wid] = __ballot(w != 0);
    __syncthreads();
    bool any = (wid < 2) ? ((blds[0] | blds[1]) != 0ull) : ((blds[2] | blds[3]) != 0ull);
    P.mw[(size_t)r0*128 + word] = any ? w : 0xffffffffu;
  }
}

// ---------------- GEMM: C[M,N] = A[M,K] * Bt[N,K]^T, bf16 MFMA -------------
// Multi-job dispatch (2 jobs/launch), geometry runtime, EPILOGUE COMPILE-TIME.
// epi 0 = bf16 (+QSCALE cols<scale_cols), 1 = bf16+ReLU, 2 = fp32+residual,
// 3 = KV split, 4 = bf16 + row bias, 5 = fp32 split-K partial.
struct GemmJob {
  const u16* A; const u16* Bt; const float* bias;
  float* outf; u16* outb; const float* res; u16* out2;
  int M, N, K, lda, k0, ksplit, scale_cols, T1, rows_per_b, vstride, swz, brmap, blk0, nblk;
};
struct GemmJobs { GemmJob j[2]; int njobs; };

template<int EPI>
__device__ __forceinline__ void epi_store(const GemmJob& J, f32x4 (&acc)[4][4],
    int m0, int n0, int wm, int wn, int lg, int l15, int ksp){
  if (EPI == 3){
    float bv[4];
    #pragma unroll
    for (int ni=0;ni<4;ni++) bv[ni] = J.bias[n0 + wn*64 + ni*16 + l15];
    #pragma unroll
    for (int ni=0;ni<4;ni++){
      int c = n0 + wn*64 + ni*16 + l15;
      #pragma unroll
      for (int mi=0;mi<4;mi++){
        int mr0 = m0 + wm*64 + mi*16 + lg*4;
        if (mr0 >= J.M) continue;
        if (c < J.T1){
          #pragma unroll
          for (int r4=0;r4<4;r4++)
            J.outb[(size_t)(mr0+r4)*J.T1 + c] = f2bf(acc[mi][ni][r4] + bv[ni]);
        } else {
          int bidx = mr0 / J.rows_per_b;
          int key  = mr0 - bidx*J.rows_per_b;
          uint2 o;
          o.x = (u32)f2bf(acc[mi][ni][0]+bv[ni]) | ((u32)f2bf(acc[mi][ni][1]+bv[ni])<<16);
          o.y = (u32)f2bf(acc[mi][ni][2]+bv[ni]) | ((u32)f2bf(acc[mi][ni][3]+bv[ni])<<16);
          *(uint2*)(J.out2 + ((size_t)bidx*512 + (c - J.T1))*J.vstride + key) = o;
        }
      }
    }
  } else if (EPI == 4){
    #pragma unroll
    for (int mi=0;mi<4;mi++){
      #pragma unroll
      for (int r4=0;r4<4;r4++){
        int m = m0 + wm*64 + mi*16 + lg*4 + r4;
        if (m >= J.M) continue;
        float rb = J.bias[m];
        #pragma unroll
        for (int ni=0;ni<4;ni++){
          int c = n0 + wn*64 + ni*16 + l15;
          J.outb[(size_t)m*J.N + c] = f2bf(acc[mi][ni][r4] + rb);
        }
      }
    }
  } else if (EPI == 5){
    float* po_ = J.outf + (size_t)ksp*J.M*J.N;
    #pragma unroll
    for (int mi=0;mi<4;mi++){
      #pragma unroll
      for (int r4=0;r4<4;r4++){
        int m = m0 + wm*64 + mi*16 + lg*4 + r4;
        if (m >= J.M) continue;
        #pragma unroll
        for (int ni=0;ni<4;ni++){
          int c = n0 + wn*64 + ni*16 + l15;
          po_[(size_t)m*J.N + c] = acc[mi][ni][r4];
        }
      }
    }
  } else {
    float bv[4], scl[4];
    #pragma unroll
    for (int ni=0;ni<4;ni++){
      int c = n0 + wn*64 + ni*16 + l15;
      bv[ni]  = J.bias[c];
      scl[ni] = (c < J.scale_cols) ? QSCALE : 1.0f;
    }
    #pragma unroll
    for (int mi=0;mi<4;mi++){
      #pragma unroll
      for (int r4=0;r4<4;r4++){
        int m = m0 + wm*64 + mi*16 + lg*4 + r4;
        if (m >= J.M) continue;
        #pragma unroll
        for (int ni=0;ni<4;ni++){
          int c = n0 + wn*64 + ni*16 + l15;
          float v = acc[mi][ni][r4] + bv[ni];
          if (EPI == 0){
            J.outb[(size_t)m*J.N + c] = f2bf(v*scl[ni]);
          } else if (EPI == 1){
            J.outb[(size_t)m*J.N + c] = f2bf(fmaxf(v, 0.0f));
          } else {
            J.outf[(size_t)m*J.N + c] = v + J.res[(size_t)m*J.N + c];
          }
        }
      }
    }
  }
}

template<int EPI>
__device__ __forceinline__ void gemm_block(const GemmJob& J, int bidIn, u16* As, u16* Bs){
  int bid = bidIn;
  int ksp = 0;
  if (J.ksplit > 1){ ksp = bid / J.nblk; bid = bid % J.nblk; }
  if (J.swz){ int cpx = J.nblk >> 3; bid = (bid & 7)*cpx + (bid >> 3); }
  int NT = J.N >> 7;
  int mt = bid / NT, nt = bid % NT;
  int m0 = mt << 7, n0 = nt << 7;
  int kofs = J.k0 + ksp * J.K;
  int tid = threadIdx.x;
  int wid = tid >> 6, lane = tid & 63;
  int wm = wid >> 1, wn = wid & 1;
  int lg = lane >> 4, l15 = lane & 15;

  f32x4 acc[4][4] = {};
  int ktiles = J.K >> 6;
  for (int kt = 0; kt < ktiles; ++kt){
    int k0 = kofs + (kt << 6);
    if (kt) __syncthreads();
    #pragma unroll
    for (int i=0;i<4;i++){
      int L = i*4096 + tid*16;
      int T = L ^ (((L>>7)&7)<<4);
      int row = T >> 7, colb = T & 127;
      int ga = m0 + row; if (ga > J.M-1) ga = J.M-1;
      gl_lds16((const char*)J.A + ((size_t)ga*J.lda + k0)*2 + colb, (char*)As + L);
    }
    #pragma unroll
    for (int i=0;i<4;i++){
      int L = i*4096 + tid*16;
      int T = L ^ (((L>>7)&7)<<4);
      int row = T >> 7, colb = T & 127;
      int rowg = n0 + row;
      if (J.brmap){ int rb = rowg & 127; rowg = (rowg>>7)*J.brmap + (rb < J.brmap ? rb : J.brmap-1); }
      gl_lds16((const char*)J.Bt + ((size_t)rowg*J.lda + k0)*2 + colb, (char*)Bs + L);
    }
    __syncthreads();
    #pragma unroll
    for (int ks=0; ks<2; ++ks){
      bf16x8 af[4], bfr[4];
      #pragma unroll
      for (int mi=0; mi<4; ++mi){
        int r = wm*64 + mi*16 + l15;
        int byt = r*128 + ks*64 + lg*16;
        af[mi] = *(const bf16x8*)((const char*)As + (byt ^ ((r&7)<<4)));
      }
      #pragma unroll
      for (int ni=0; ni<4; ++ni){
        int r = wn*64 + ni*16 + l15;
        int byt = r*128 + ks*64 + lg*16;
        bfr[ni] = *(const bf16x8*)((const char*)Bs + (byt ^ ((r&7)<<4)));
      }
      __builtin_amdgcn_s_setprio(1);
      #pragma unroll
      for (int mi=0;mi<4;mi++)
        #pragma unroll
        for (int ni=0;ni<4;ni++)
          acc[mi][ni] = __builtin_amdgcn_mfma_f32_16x16x32_bf16(af[mi], bfr[ni], acc[mi][ni], 0,0,0);
      __builtin_amdgcn_s_setprio(0);
    }
  }
  epi_store<EPI>(J, acc, m0, n0, wm, wn, lg, l15, ksp);
}

template<int EPIA, int EPIB>
__global__ __launch_bounds__(256) void gemm_multi(GemmJobs G){
  __shared__ __align__(16) u16 As[8192];
  __shared__ __align__(16) u16 Bs[8192];
  bool second = (G.njobs > 1) && ((int)blockIdx.x >= G.j[1].blk0);
  if (second) gemm_block<EPIB>(G.j[1], (int)blockIdx.x - G.j[1].blk0, As, Bs);
  else        gemm_block<EPIA>(G.j[0], (int)blockIdx.x, As, Bs);
}

// ---------------- 256x256-tile GEMM, 8 waves, k-split phases, counted vmcnt -
// K=512 fixed (KT=8 tiles of BK=64, each 2 k-halves of 32). LDS 128KB.
// Swizzle: 16B slot s stored at s^((row>>1)&3) — spreads each 16-lane
// quarter-group across all 8 chunk-bank columns (R15 fix: row&3 left
// quarter-groups on 4/8 columns -> 2-way serialization, 3.2M conflicts).
struct G256Job {
  const u16* A; const u16* Bt; const float* bias;
  u16* outb; u16* out2;
  int M, N, lda, epi, nblk, swz;
};

__global__ __launch_bounds__(512, 2) void gemm256(G256Job J0, G256Job J1, int blk1, int njobs){
  __shared__ __align__(16) char lds[131072];
  G256Job J = J0;
  int lb = blockIdx.x;
  if (njobs > 1 && lb >= blk1){ J = J1; lb -= blk1; }
  if (J.swz){ int cpx = J.nblk >> 3; lb = (lb & 7)*cpx + (lb >> 3); }
  int NT = J.N >> 8;
  int mt = lb / NT, nt = lb % NT;
  int m0 = mt << 8, n0 = nt << 8;
  int tid = threadIdx.x;
  int wid = tid >> 6, lane = tid & 63;
  int wm = wid >> 2, wn = wid & 3;
  int lg = lane >> 4, l15 = lane & 15;
  const int KT = 8;
  char* Al = lds;
  char* Bl = lds + 65536;

  auto stage_pair = [&](int t, int h){
    int bufo = ((t & 1) << 15) | (h << 14);
    #pragma unroll
    for (int i=0;i<2;i++){
      int idx = i*512 + tid;
      int row = idx >> 2, s = idx & 3;
      int sg = s ^ ((row >> 1) & 3);
      int ga = m0 + row; if (ga > J.M-1) ga = J.M-1;
      gl_lds16((const char*)J.A + ((size_t)ga*J.lda + t*64 + h*32 + sg*8)*2,
               Al + bufo + idx*16);
    }
    #pragma unroll
    for (int i=0;i<2;i++){
      int idx = i*512 + tid;
      int row = idx >> 2, s = idx & 3;
      int sg = s ^ ((row >> 1) & 3);
      gl_lds16((const char*)J.Bt + ((size_t)(n0 + row)*J.lda + t*64 + h*32 + sg*8)*2,
               Bl + bufo + idx*16);
    }
  };

  f32x4 acc[8][4] = {};
  stage_pair(0, 0);
  stage_pair(0, 1);
  for (int t=0; t<KT; ++t){
    #pragma unroll
    for (int h=0; h<2; ++h){
      if (t+1 < KT){
        stage_pair(t+1, h);
        asm volatile("s_waitcnt vmcnt(8)" ::: "memory");
      } else if (h == 0){
        asm volatile("s_waitcnt vmcnt(4)" ::: "memory");
      } else {
        asm volatile("s_waitcnt vmcnt(0)" ::: "memory");
      }
      __builtin_amdgcn_s_barrier();
      int bufo = ((t & 1) << 15) | (h << 14);
      bf16x8 af[8], bfr[4];
      #pragma unroll
      for (int ni=0;ni<4;ni++){
        int row = wn*64 + ni*16 + l15;
        bfr[ni] = *(const bf16x8*)(Bl + bufo + row*64 + ((lg ^ ((row>>1)&3))<<4));
      }
      #pragma unroll
      for (int mi=0;mi<8;mi++){
        int row = wm*128 + mi*16 + l15;
        af[mi] = *(const bf16x8*)(Al + bufo + row*64 + ((lg ^ ((row>>1)&3))<<4));
      }
      __builtin_amdgcn_s_setprio(1);
      #pragma unroll
      for (int mi=0;mi<8;mi++)
        #pragma unroll
        for (int ni=0;ni<4;ni++)
          acc[mi][ni] = __builtin_amdgcn_mfma_f32_16x16x32_bf16(af[mi], bfr[ni], acc[mi][ni], 0,0,0);
      __builtin_amdgcn_s_setprio(0);
      __builtin_amdgcn_s_barrier();
    }
  }

  float bv[4];
  #pragma unroll
  for (int ni=0;ni<4;ni++) bv[ni] = J.bias[n0 + wn*64 + ni*16 + l15];
  if (J.epi == 0){
    #pragma unroll
    for (int mi=0;mi<8;mi++){
      #pragma unroll
      for (int r=0;r<4;r++){
        int m = m0 + wm*128 + mi*16 + lg*4 + r;
        if (m >= J.M) continue;
        #pragma unroll
        for (int ni=0;ni<4;ni++){
          int c = n0 + wn*64 + ni*16 + l15;
          J.outb[(size_t)m*J.N + c] = f2bf((acc[mi][ni][r] + bv[ni])*QSCALE);
        }
      }
    }
  } else if (n0 < 512){
    // K half -> kp row-major [M][512]
    #pragma unroll
    for (int mi=0;mi<8;mi++){
      #pragma unroll
      for (int r=0;r<4;r++){
        int m = m0 + wm*128 + mi*16 + lg*4 + r;
        #pragma unroll
        for (int ni=0;ni<4;ni++){
          int c = n0 + wn*64 + ni*16 + l15;
          J.outb[(size_t)m*512 + c] = f2bf(acc[mi][ni][r] + bv[ni]);
        }
      }
    }
  } else {
    // V half -> vpT[(bidx*512 + f)*4096 + key]
    #pragma unroll
    for (int ni=0;ni<4;ni++){
      int f = n0 - 512 + wn*64 + ni*16 + l15;
      #pragma unroll
      for (int mi=0;mi<8;mi++){
        int m = m0 + wm*128 + mi*16 + lg*4;
        int bidx = m >> 12, key = m & 4095;
        uint2 o;
        o.x = (u32)f2bf(acc[mi][ni][0]+bv[ni]) | ((u32)f2bf(acc[mi][ni][1]+bv[ni])<<16);
        o.y = (u32)f2bf(acc[mi][ni][2]+bv[ni]) | ((u32)f2bf(acc[mi][ni][3]+bv[ni])<<16);
        *(uint2*)(J.out2 + ((size_t)bidx*512 + f)*4096 + key) = o;
      }
    }
  }
}

// split-K reduce: out = res + bias[c] + sum_s part[s]; 4 floats per thread
__global__ __launch_bounds__(256) void splitk_reduce(
    const float* __restrict__ part, int nsplit, const float* __restrict__ bias,
    const float* __restrict__ res, float* __restrict__ out, int N, int total4)
{
  int idx = (blockIdx.x*256 + threadIdx.x);
  if (idx >= total4) return;
  int e0 = idx*4;
  size_t MN = (size_t)total4*4;
  float4 a = *(const float4*)(part + e0);
  #pragma unroll
  for (int s=1;s<4;s++){
    float4 p = *(const float4*)(part + s*MN + e0);
    a.x += p.x; a.y += p.y; a.z += p.z; a.w += p.w;
  }
  float4 r = *(const float4*)(res + e0);
  int c = e0 & (N-1);
  float4 bv = *(const float4*)(bias + c);
  float4 o;
  o.x = a.x + r.x + bv.x; o.y = a.y + r.y + bv.y;
  o.z = a.z + r.z + bv.z; o.w = a.w + r.w + bv.w;
  *(float4*)(out + e0) = o;
}

// ---------------- flash attention: 64-key tiles, 2-buf counted-vmcnt pipe ---
template<bool PARTIAL, bool HASMASK, int NTILES>
__global__ __launch_bounds__(256) void attn_kernel(
    const u16* __restrict__ Qp, int ldq,
    const u16* __restrict__ Kp, int ldk, int kcol0,
    const u16* __restrict__ VT, size_t vbs, int vfs,
    const u32* __restrict__ maskw,
    float* __restrict__ pm, float* __restrict__ pl, u16* __restrict__ po,
    u16* __restrict__ o_out,
    int nq, int mk, int S, int H, int Bp, int swz)
{
  __shared__ __align__(16) u16 Ks[2*4096];
  __shared__ __align__(16) u16 Vs[2*4096];
  int bid = blockIdx.x;
  if (swz){ int cpx = gridDim.x >> 3; bid = (bid & 7)*cpx + (bid >> 3); }
  int s = bid % S; int h = (bid / S) % H; int b = bid / (S*H);
  int tid = threadIdx.x, wid = tid>>6, lane = tid&63;
  int lg = lane>>4, l15 = lane&15;
  int qbase = b*nq;
  int kps = mk / S;
  int kbeg = s * kps;
  int mwld = mk >> 5;
  int krel = lg*4;

  bf16x8 qf[2][2];
  #pragma unroll
  for (int mt=0;mt<2;mt++){
    int qr = wid*32 + mt*16 + l15; int qc = qr < nq ? qr : nq-1;
    #pragma unroll
    for (int ks=0;ks<2;ks++)
      qf[mt][ks] = *(const bf16x8*)(Qp + (size_t)(qbase+qc)*ldq + h*64 + ks*32 + lg*8);
  }
  u32 wmw[2][2*NTILES];
  if (HASMASK){
    #pragma unroll
    for (int mt=0;mt<2;mt++){
      int qc = (wid*32 + mt*16 + l15) < nq ? (wid*32 + mt*16 + l15) : nq-1;
      const u32* mrow = maskw + (size_t)(qbase+qc)*mwld + (kbeg>>5);
      #pragma unroll
      for (int wi=0; wi<2*NTILES; wi+=4){
        uint4 v = *(const uint4*)(mrow + wi);
        wmw[mt][wi+0]=v.x; wmw[mt][wi+1]=v.y; wmw[mt][wi+2]=v.z; wmw[mt][wi+3]=v.w;
      }
    }
  }

  float m_r[2] = {NEG_INF, NEG_INF};
  float l_r[2] = {0.0f, 0.0f};
  f32x4 of[2][4] = {};

  auto stage = [&](int t_, int bufi){
    int kb_ = kbeg + t_*64;
    #pragma unroll
    for (int i=0;i<2;i++){
      int idx = i*256 + tid;
      int key = idx>>3, sd = idx&7;
      int kc = kb_ + key; if (kc > mk-1) kc = mk-1;
      const char* src = (const char*)(Kp + (size_t)(b*mk + kc)*ldk + kcol0 + h*64) + ((sd ^ (key&7))<<4);
      gl_lds16(src, (char*)Ks + bufi*8192 + idx*16);
    }
    #pragma unroll
    for (int i=0;i<2;i++){
      int idx = i*256 + tid;
      int f = idx>>3, sd = idx&7;
      const char* src = (const char*)(VT + (size_t)b*vbs + (size_t)(h*64+f)*vfs + kb_) + ((sd ^ (f&7))<<4);
      gl_lds16(src, (char*)Vs + bufi*8192 + idx*16);
    }
  };

  stage(0, 0);

  #pragma unroll
  for (int t=0;t<NTILES;t++){
    if (t+1 < NTILES){
      stage(t+1, (t+1)&1);
      asm volatile("s_waitcnt vmcnt(4)" ::: "memory");
    } else {
      asm volatile("s_waitcnt vmcnt(0)" ::: "memory");
    }
    __builtin_amdgcn_s_barrier();

    const char* Kb = (const char*)Ks + (t&1)*8192;
    const char* Vb = (const char*)Vs + (t&1)*8192;
    int kb = kbeg + t*64;

    f32x4 sT[4][2] = {};
    #pragma unroll
    for (int nt2=0;nt2<4;nt2++){
      bf16x8 k0 = *(const bf16x8*)(Kb + ((nt2*16+l15)<<7) + (((lg  ) ^ (l15&7))<<4));
      bf16x8 k1 = *(const bf16x8*)(Kb + ((nt2*16+l15)<<7) + (((4+lg) ^ (l15&7))<<4));
      __builtin_amdgcn_s_setprio(1);
      #pragma unroll
      for (int mt=0;mt<2;mt++){
        sT[nt2][mt] = __builtin_amdgcn_mfma_f32_16x16x32_bf16(k0, qf[mt][0], sT[nt2][mt], 0,0,0);
        sT[nt2][mt] = __builtin_amdgcn_mfma_f32_16x16x32_bf16(k1, qf[mt][1], sT[nt2][mt], 0,0,0);
      }
      __builtin_amdgcn_s_setprio(0);
    }

    s16x4 pb[2][4];
    #pragma unroll
    for (int mt=0;mt<2;mt++){
      float mx = NEG_INF;
      #pragma unroll
      for (int nt2=0;nt2<4;nt2++){
        u32 wb = 0;
        if (HASMASK) wb = wmw[mt][t*2 + (nt2>>1)] >> (((nt2&1)<<4) + krel);
        #pragma unroll
        for (int r=0;r<4;r++){
          bool ok = HASMASK ? (((wb>>r)&1u) != 0) : (kb + nt2*16 + krel + r < mk);
          float sv = ok ? sT[nt2][mt][r] : NEG_INF;
          sT[nt2][mt][r] = sv;
          mx = fmaxf(mx, sv);
        }
      }
      mx = fmaxf(mx, __shfl_xor(mx, 16, 64));
      mx = fmaxf(mx, __shfl_xor(mx, 32, 64));
      if (!__all(mx <= m_r[mt] + 8.0f)){
        float mnew = fmaxf(m_r[mt], mx);
        float corr = exp2f(m_r[mt] - mnew);
        m_r[mt] = mnew;
        l_r[mt] *= corr;
        #pragma unroll
        for (int nf=0;nf<4;nf++) of[mt][nf] *= corr;
      }
      float ps = 0.0f;
      #pragma unroll
      for (int nt2=0;nt2<4;nt2++)
        #pragma unroll
        for (int r=0;r<4;r++){
          float p = exp2f(sT[nt2][mt][r] - m_r[mt]);
          ps += p;
          pb[mt][nt2][r] = f2bf_s(p);
        }
      ps += __shfl_xor(ps, 16, 64);
      ps += __shfl_xor(ps, 32, 64);
      l_r[mt] += ps;
    }

    #pragma unroll
    for (int nf=0;nf<4;nf++){
      s16x4 vf[4];
      #pragma unroll
      for (int nt2=0;nt2<4;nt2++){
        int slot = (nt2*2 + (lg>>1)) ^ (l15&7);
        vf[nt2] = *(const s16x4*)(Vb + ((nf*16+l15)<<7) + (slot<<4) + ((lg&1)<<3));
      }
      __builtin_amdgcn_s_setprio(1);
      #pragma unroll
      for (int mt=0;mt<2;mt++)
        #pragma unroll
        for (int nt2=0;nt2<4;nt2++)
          of[mt][nf] = mfma16(vf[nt2], pb[mt][nt2], of[mt][nf]);
      __builtin_amdgcn_s_setprio(0);
    }
    __builtin_amdgcn_s_barrier();
  }

  #pragma unroll
  for (int mt=0;mt<2;mt++){
    int q = wid*32 + mt*16 + l15;
    if (q < nq){
      if (PARTIAL){
        size_t base = (((size_t)(s*Bp + b)*H + h)*128 + q);
        if (lg == 0){ pm[base] = m_r[mt]; pl[base] = l_r[mt]; }
        #pragma unroll
        for (int nf=0;nf<4;nf++){
          uint2 o;
          o.x = (u32)f2bf(of[mt][nf][0]) | ((u32)f2bf(of[mt][nf][1])<<16);
          o.y = (u32)f2bf(of[mt][nf][2]) | ((u32)f2bf(of[mt][nf][3])<<16);
          *(uint2*)(po + base*64 + nf*16 + lg*4) = o;
        }
      } else {
        float inv = 1.0f / l_r[mt];
        #pragma unroll
        for (int nf=0;nf<4;nf++){
          uint2 o;
          o.x = (u32)f2bf(of[mt][nf][0]*inv) | ((u32)f2bf(of[mt][nf][1]*inv)<<16);
          o.y = (u32)f2bf(of[mt][nf][2]*inv) | ((u32)f2bf(of[mt][nf][3]*inv)<<16);
          *(uint2*)(o_out + (size_t)(qbase+q)*512 + h*64 + nf*16 + lg*4) = o;
        }
      }
    }
  }
}

__global__ __launch_bounds__(64) void attn_combine(
    const float* __restrict__ pm, const float* __restrict__ pl, const u16* __restrict__ po,
    u16* __restrict__ o_out, int S, int Bp, int H, int nq)
{
  int bid = blockIdx.x;
  int q = bid % nq; int h = (bid / nq) % H; int b = bid / (nq*H);
  int f = threadIdx.x;
  float mstar = NEG_INF;
  for (int s=0;s<S;s++){
    size_t idx = (((size_t)(s*Bp + b)*H + h)*128 + q);
    mstar = fmaxf(mstar, pm[idx]);
  }
  float L = 0.0f, acc = 0.0f;
  for (int s=0;s<S;s++){
    size_t idx = (((size_t)(s*Bp + b)*H + h)*128 + q);
    float w = exp2f(pm[idx] - mstar);
    L += w * pl[idx];
    acc += w * bf2f(po[idx*64 + f]);
  }
  o_out[((size_t)b*nq + q)*512 + h*64 + f] = f2bf(acc / L);
}

// ---------------------------------------------------------------------------
extern "C" void kernel_launch(void* const* d_in, const int* in_sizes, int n_in,
                              void* d_out, int out_size, void* d_ws, size_t ws_size,
                              hipStream_t stream){
  const float* q_in    = (const float*)d_in[0];
  const float* kv_in   = (const float*)d_in[1];
  const int*   maskb   = (const int*)d_in[2];
  const float* xa_Wqkv = (const float*)d_in[3];
  const float* xa_bqkv = (const float*)d_in[4];
  const float* xa_Wo   = (const float*)d_in[5];
  const float* xa_bo   = (const float*)d_in[6];
  const float* xa_gq   = (const float*)d_in[7];
  const float* xa_bq   = (const float*)d_in[8];
  const float* xa_gkv  = (const float*)d_in[9];
  const float* xa_bkv  = (const float*)d_in[10];
  const float* sa_Wqkv = (const float*)d_in[11];
  const float* sa_bqkv = (const float*)d_in[12];
  const float* sa_Wo   = (const float*)d_in[13];
  const float* sa_bo   = (const float*)d_in[14];
  const float* n1_g = (const float*)d_in[15];
  const float* n1_b = (const float*)d_in[16];
  const float* n2_g = (const float*)d_in[17];
  const float* n2_b = (const float*)d_in[18];
  const float* ff_W1 = (const float*)d_in[19];
  const float* ff_b1 = (const float*)d_in[20];
  const float* ff_W2 = (const float*)d_in[21];
  const float* ff_b2 = (const float*)d_in[22];

  char* ws = (char*)d_ws;
  size_t off = 0;
  auto alloc = [&](size_t bytes)->char*{ char* p = ws + off; off = (off + bytes + 255) & ~(size_t)255; return p; };
  u16* wq  = (u16*)alloc((size_t)512*512*2);
  u16* wkv = (u16*)alloc((size_t)1024*512*2);
  u16* wsa = (u16*)alloc((size_t)1536*512*2);
  u16* wxo = (u16*)alloc((size_t)512*512*2);
  u16* wso = (u16*)alloc((size_t)512*512*2);
  u16* wf1 = (u16*)alloc((size_t)2048*512*2);
  u16* wf2 = (u16*)alloc((size_t)512*2048*2);
  u16* qn  = (u16*)alloc((size_t)800*512*2);
  u16* qp  = (u16*)alloc((size_t)800*512*2);
  u32* mw  = (u32*)alloc((size_t)800*128*4);
  u16* kp  = (u16*)alloc((size_t)32768*512*2);
  u16* vpT = (u16*)alloc((size_t)8*512*4096*2);   // [(b*512+f)][4096 keys]
  size_t reuse_off = off;
  u16* kvn = (u16*)alloc((size_t)32768*512*2);
  size_t offB = reuse_off;
  auto allocB = [&](size_t bytes)->char*{ char* p = ws + offB; offB = (offB + bytes + 255) & ~(size_t)255; return p; };
  const int S = 16;
  float* pm   = (float*)allocB((size_t)S*64*128*4);
  float* pl   = (float*)allocB((size_t)S*64*128*4);
  u16*   po   = (u16*)allocB((size_t)S*64*128*64*2);
  u16* o_xa   = (u16*)allocB((size_t)800*512*2);
  float* x1   = (float*)allocB((size_t)800*512*4);
  u16* qn1    = (u16*)allocB((size_t)800*512*2);
  u16* saqkv  = (u16*)allocB((size_t)800*1024*2);
  u16* vT2sa  = (u16*)allocB((size_t)512*1024*2);
  u16* o_sa   = (u16*)allocB((size_t)800*512*2);
  float* x2   = (float*)allocB((size_t)800*512*4);
  u16* qn2    = (u16*)allocB((size_t)800*512*2);
  u16* hbuf   = (u16*)allocB((size_t)800*2048*2);
  // split-K partials (FFN2): 4 x 800x512 fp32; alias dead pm/pl/po region
  float* fpart = pm;

  // ---- single prep dispatch: 7 wtrans jobs + LN(q) + LN(kv) + mask --------
  PrepArgs P;
  P.wt.W[0]=xa_Wqkv; P.wt.Wt[0]=wq;  P.wt.K[0]=512;  P.wt.Nfull[0]=1536; P.wt.ncol0[0]=0;   P.wt.nt[0]=16;
  P.wt.W[1]=xa_Wqkv; P.wt.Wt[1]=wkv; P.wt.K[1]=512;  P.wt.Nfull[1]=1536; P.wt.ncol0[1]=512; P.wt.nt[1]=32;
  P.wt.W[2]=sa_Wqkv; P.wt.Wt[2]=wsa; P.wt.K[2]=512;  P.wt.Nfull[2]=1536; P.wt.ncol0[2]=0;   P.wt.nt[2]=48;
  P.wt.W[3]=xa_Wo;   P.wt.Wt[3]=wxo; P.wt.K[3]=512;  P.wt.Nfull[3]=512;  P.wt.ncol0[3]=0;   P.wt.nt[3]=16;
  P.wt.W[4]=sa_Wo;   P.wt.Wt[4]=wso; P.wt.K[4]=512;  P.wt.Nfull[4]=512;  P.wt.ncol0[4]=0;   P.wt.nt[4]=16;
  P.wt.W[5]=ff_W1;   P.wt.Wt[5]=wf1; P.wt.K[5]=512;  P.wt.Nfull[5]=2048; P.wt.ncol0[5]=0;   P.wt.nt[5]=64;
  P.wt.W[6]=ff_W2;   P.wt.Wt[6]=wf2; P.wt.K[6]=2048; P.wt.Nfull[6]=512;  P.wt.ncol0[6]=0;   P.wt.nt[6]=16;
  int tot = 0;
  for (int i=0;i<7;i++){ P.wt.blk0[i] = tot; tot += (P.wt.K[i]/32)*P.wt.nt[i]; }
  P.totW = tot;
  P.x0=q_in;  P.g0=xa_gq;  P.b0=xa_bq;  P.o0=qn;  P.nb0=200;  P.rows0=800;
  P.x1=kv_in; P.g1=xa_gkv; P.b1=xa_bkv; P.o1=kvn; P.nb1=8192; P.rows1=32768;
  P.mask=maskb; P.mw=mw;
  prep_all<<<tot + 200 + 8192 + 400, 256, 0, stream>>>(P);

  auto mkjob = [&](const u16*A, const u16*Bt, const float*bias, float*outf, u16*outb,
                   const float*res, u16*out2, int M, int N, int K, int lda, int k0,
                   int ksplit, int sc, int T1, int rpb, int vst, int swz, int brm,
                   int blk0, int nblk)->GemmJob{
    GemmJob j; j.A=A; j.Bt=Bt; j.bias=bias; j.outf=outf; j.outb=outb; j.res=res; j.out2=out2;
    j.M=M; j.N=N; j.K=K; j.lda=lda; j.k0=k0; j.ksplit=ksplit; j.scale_cols=sc; j.T1=T1;
    j.rows_per_b=rpb; j.vstride=vst; j.swz=swz; j.brmap=brm; j.blk0=blk0; j.nblk=nblk;
    return j;
  };

  // ---- 256^2 phased GEMM: KV projection (512 blk) || Q projection (8 blk) --
  {
    G256Job jkv, jq;
    jkv.A = kvn; jkv.Bt = wkv; jkv.bias = xa_bqkv+512; jkv.outb = kp; jkv.out2 = vpT;
    jkv.M = 32768; jkv.N = 1024; jkv.lda = 512; jkv.epi = 3; jkv.nblk = 512; jkv.swz = 1;
    jq.A = qn; jq.Bt = wq; jq.bias = xa_bqkv; jq.outb = qp; jq.out2 = nullptr;
    jq.M = 800; jq.N = 512; jq.lda = 512; jq.epi = 0; jq.nblk = 8; jq.swz = 0;
    gemm256<<<512 + 8, 512, 0, stream>>>(jkv, jq, 512, 2);
  }
  attn_kernel<true,true,4><<<8*8*S, 256, 0, stream>>>(
      qp, 512, kp, 512, 0, vpT, (size_t)512*4096, 4096, mw,
      pm, pl, po, nullptr, 100, 4096, S, 8, 8, 1);
  attn_combine<<<8*8*100, 64, 0, stream>>>(pm, pl, po, o_xa, S, 8, 8, 100);
  {
    GemmJobs g;
    g.j[0] = mkjob(o_xa, wxo, xa_bo, x1, nullptr, q_in, nullptr,
                   800, 512, 512, 512, 0, 1, 0, 0,1,1, 0,0, 0, 28);
    g.j[1] = g.j[0]; g.njobs = 1;
    gemm_multi<2,2><<<28, 256, 0, stream>>>(g);
  }
  ln_rows<<<200, 256, 0, stream>>>(x1, n1_g, n1_b, qn1, 800);
  {
    GemmJobs g;
    g.j[0] = mkjob(qn1, wsa, sa_bqkv, nullptr, saqkv, nullptr, nullptr,
                   800, 1024, 512, 512, 0, 1, 512, 0,1,1, 0,0, 0, 56);
    g.j[1] = mkjob(wsa + (size_t)1024*512, qn1, sa_bqkv+1024, nullptr, vT2sa, nullptr, nullptr,
                   512, 1024, 512, 512, 0, 1, 0, 0,1,1, 0, 100, 56, 32);
    g.njobs = 2;
    gemm_multi<0,4><<<56 + 32, 256, 0, stream>>>(g);
  }
  attn_kernel<false,false,2><<<64, 256, 0, stream>>>(
      saqkv, 1024, saqkv, 1024, 512, vT2sa, (size_t)128, 1024, nullptr,
      nullptr, nullptr, nullptr, o_sa, 100, 100, 1, 8, 8, 0);
  {
    GemmJobs g;
    g.j[0] = mkjob(o_sa, wso, sa_bo, x2, nullptr, x1, nullptr,
                   800, 512, 512, 512, 0, 1, 0, 0,1,1, 0,0, 0, 28);
    g.j[1] = g.j[0]; g.njobs = 1;
    gemm_multi<2,2><<<28, 256, 0, stream>>>(g);
  }
  ln_rows<<<200, 256, 0, stream>>>(x2, n2_g, n2_b, qn2, 800);
  {
    GemmJobs g;
    g.j[0] = mkjob(qn2, wf1, ff_b1, nullptr, hbuf, nullptr, nullptr,
                   800, 2048, 512, 512, 0, 1, 0, 0,1,1, 0,0, 0, 112);
    g.j[1] = g.j[0]; g.njobs = 1;
    gemm_multi<1,1><<<112, 256, 0, stream>>>(g);
  }
  // FFN2: split-K x4 (K=2048 -> 4x512), fp32 partials into dead attn scratch
  {
    GemmJobs g;
    g.j[0] = mkjob(hbuf, wf2, nullptr, fpart, nullptr, nullptr, nullptr,
                   800, 512, 512, 2048, 0, 4, 0, 0,1,1, 0,0, 0, 28);
    g.j[1] = g.j[0]; g.njobs = 1;
    gemm_multi<5,5><<<112, 256, 0, stream>>>(g);
  }
  splitk_reduce<<<(800*512/4 + 255)/256, 256, 0, stream>>>(
      fpart, 4, ff_b2, x2, (float*)d_out, 512, 800*512/4);
}

// Round 17
// 220.176 us; speedup vs baseline: 1.0591x; 1.0531x over previous
//
#include <hip/hip_runtime.h>

typedef unsigned short u16;
typedef unsigned int u32;
typedef __bf16 bf16x8 __attribute__((ext_vector_type(8)));
typedef short s16x4 __attribute__((ext_vector_type(4)));
typedef float f32x4 __attribute__((ext_vector_type(4)));

#define NEG_INF -3.0e38f
#define QSCALE 0.18033688011f   // 0.125 * log2(e): softmax done in exp2 domain

__device__ __forceinline__ u16 f2bf(float f){
  union { float f; u32 u; } v; v.f = f;
  u32 r = v.u + 0x7fffu + ((v.u >> 16) & 1u);
  return (u16)(r >> 16);
}
__device__ __forceinline__ float bf2f(u16 h){
  union { u32 u; float f; } v; v.u = ((u32)h) << 16; return v.f;
}
__device__ __forceinline__ short f2bf_s(float f){
  union { __bf16 h; short s; } cv; cv.h = (__bf16)f; return cv.s;
}

__device__ __forceinline__ f32x4 mfma16(s16x4 a, s16x4 b, f32x4 c){
#if __has_builtin(__builtin_amdgcn_mfma_f32_16x16x16bf16_1k)
  return __builtin_amdgcn_mfma_f32_16x16x16bf16_1k(a, b, c, 0, 0, 0);
#else
  asm("v_mfma_f32_16x16x16_bf16 %0, %1, %2, %0" : "+v"(c) : "v"(a), "v"(b));
  return c;
#endif
}

__device__ __forceinline__ void gl_lds16(const void* g, void* l){
  __builtin_amdgcn_global_load_lds((const __attribute__((address_space(1))) void*)g,
      (__attribute__((address_space(3))) void*)l, 16, 0, 0);
}

// ---------------- LayerNorm rows of 512, fp32 in -> bf16 out ----------------
__device__ __forceinline__ void ln_body(const float* __restrict__ xr,
    const float* __restrict__ g, const float* __restrict__ b,
    u16* __restrict__ orow, int lane){
  float4 v0 = *(const float4*)(xr + lane * 4);
  float4 v1 = *(const float4*)(xr + 256 + lane * 4);
  float s = v0.x+v0.y+v0.z+v0.w + v1.x+v1.y+v1.z+v1.w;
  float q = v0.x*v0.x+v0.y*v0.y+v0.z*v0.z+v0.w*v0.w
          + v1.x*v1.x+v1.y*v1.y+v1.z*v1.z+v1.w*v1.w;
  #pragma unroll
  for (int d=1; d<64; d<<=1){ s += __shfl_xor(s, d, 64); q += __shfl_xor(q, d, 64); }
  float mean = s * (1.0f/512.0f);
  float var  = q * (1.0f/512.0f) - mean*mean;
  float rs = rsqrtf(var + 1e-5f);
  float4 g0 = *(const float4*)(g + lane*4), g1 = *(const float4*)(g + 256 + lane*4);
  float4 b0 = *(const float4*)(b + lane*4), b1 = *(const float4*)(b + 256 + lane*4);
  uint2 pa, pb;
  pa.x = (u32)f2bf((v0.x-mean)*rs*g0.x + b0.x) | ((u32)f2bf((v0.y-mean)*rs*g0.y + b0.y) << 16);
  pa.y = (u32)f2bf((v0.z-mean)*rs*g0.z + b0.z) | ((u32)f2bf((v0.w-mean)*rs*g0.w + b0.w) << 16);
  pb.x = (u32)f2bf((v1.x-mean)*rs*g1.x + b1.x) | ((u32)f2bf((v1.y-mean)*rs*g1.y + b1.y) << 16);
  pb.y = (u32)f2bf((v1.z-mean)*rs*g1.z + b1.z) | ((u32)f2bf((v1.w-mean)*rs*g1.w + b1.w) << 16);
  *(uint2*)(orow + lane*4) = pa;
  *(uint2*)(orow + 256 + lane*4) = pb;
}

__global__ __launch_bounds__(256) void ln_rows(const float* __restrict__ x,
    const float* __restrict__ g, const float* __restrict__ b,
    u16* __restrict__ out, int rows){
  int wid = threadIdx.x >> 6, lane = threadIdx.x & 63;
  int row = blockIdx.x * 4 + wid;
  if (row >= rows) return;
  ln_body(x + (size_t)row*512, g, b, out + (size_t)row*512, lane);
}

// ---------------- fused prep: 7 weight transposes + LN(q) + LN(kv) + mask ---
struct WtJobs {
  const float* W[7]; u16* Wt[7];
  int K[7], Nfull[7], ncol0[7], nt[7], blk0[7];
};
struct PrepArgs {
  WtJobs wt; int totW;
  const float *x0, *g0, *b0; u16* o0; int nb0, rows0;
  const float *x1, *g1, *b1; u16* o1; int nb1, rows1;
  const int* mask; u32* mw;
};

__global__ __launch_bounds__(256) void prep_all(PrepArgs P){
  __shared__ float tile[32][33];
  __shared__ unsigned long long blds[4];
  int bb = blockIdx.x;
  int tid = threadIdx.x;
  int wid = tid >> 6, lane = tid & 63;
  if (bb < P.totW){
    const WtJobs& J = P.wt;
    const float* W = J.W[0]; u16* Wt = J.Wt[0];
    int K = J.K[0], Nfull = J.Nfull[0], ncol0 = J.ncol0[0], nt = J.nt[0], blk0 = 0;
    #pragma unroll
    for (int i=1;i<7;i++)
      if (bb >= J.blk0[i]){
        W=J.W[i]; Wt=J.Wt[i]; K=J.K[i]; Nfull=J.Nfull[i]; ncol0=J.ncol0[i]; nt=J.nt[i]; blk0=J.blk0[i];
      }
    int lb = bb - blk0;
    int tk = lb / nt, tn = lb % nt;
    int col = tid & 31, kr = tid >> 5;
    #pragma unroll
    for (int i=0;i<4;i++){
      int k = tk*32 + kr + i*8;
      tile[kr + i*8][col] = W[(size_t)k*Nfull + ncol0 + tn*32 + col];
    }
    __syncthreads();
    int nl = tid >> 3, kc = (tid & 7) * 4;
    uint2 o;
    o.x = (u32)f2bf(tile[kc+0][nl]) | ((u32)f2bf(tile[kc+1][nl]) << 16);
    o.y = (u32)f2bf(tile[kc+2][nl]) | ((u32)f2bf(tile[kc+3][nl]) << 16);
    *(uint2*)(Wt + (size_t)(tn*32 + nl)*K + tk*32 + kc) = o;
  } else if (bb < P.totW + P.nb0){
    int row = (bb - P.totW)*4 + wid;
    if (row >= P.rows0) return;
    ln_body(P.x0 + (size_t)row*512, P.g0, P.b0, P.o0 + (size_t)row*512, lane);
  } else if (bb < P.totW + P.nb0 + P.nb1){
    int row = (bb - P.totW - P.nb0)*4 + wid;
    if (row >= P.rows1) return;
    ln_body(P.x1 + (size_t)row*512, P.g1, P.b1, P.o1 + (size_t)row*512, lane);
  } else {
    int lb = bb - P.totW - P.nb0 - P.nb1;
    int r0 = lb*2 + (wid >> 1);
    int word = tid & 127;
    const int* mr = P.mask + (size_t)r0*4096 + word*32;
    u32 w = 0;
    #pragma unroll
    for (int j=0;j<32;j+=4){
      int4 v = *(const int4*)(mr + j);
      w |= (u32)(v.x!=0) << j;
      w |= (u32)(v.y!=0) << (j+1);
      w |= (u32)(v.z!=0) << (j+2);
      w |= (u32)(v.w!=0) << (j+3);
    }
    blds[wid] = __ballot(w != 0);
    __syncthreads();
    bool any = (wid < 2) ? ((blds[0] | blds[1]) != 0ull) : ((blds[2] | blds[3]) != 0ull);
    P.mw[(size_t)r0*128 + word] = any ? w : 0xffffffffu;
  }
}

// ---------------- GEMM: C[M,N] = A[M,K] * Bt[N,K]^T, bf16 MFMA -------------
// Multi-job dispatch (2 jobs/launch), geometry runtime, EPILOGUE COMPILE-TIME
// (R9: runtime epi costs 16 VGPR / 30% occupancy).
// epi 0 = bf16 (+QSCALE cols<scale_cols), 1 = bf16+ReLU, 2 = fp32+residual,
// 3 = KV split (K row-major; V^T via per-wave LDS transpose -> coalesced),
// 4 = bf16 + row bias, 5 = fp32 split-K partial.
struct GemmJob {
  const u16* A; const u16* Bt; const float* bias;
  float* outf; u16* outb; const float* res; u16* out2;
  int M, N, K, lda, k0, ksplit, scale_cols, T1, rows_per_b, vstride, swz, brmap, blk0, nblk;
};
struct GemmJobs { GemmJob j[2]; int njobs; };

template<int EPI>
__device__ __forceinline__ void epi_store(const GemmJob& J, f32x4 (&acc)[4][4],
    int m0, int n0, int wm, int wn, int lg, int l15, int ksp, u16* smem){
  if (EPI == 3){
    float bv[4];
    #pragma unroll
    for (int ni=0;ni<4;ni++) bv[ni] = J.bias[n0 + wn*64 + ni*16 + l15];
    if (n0 + 128 <= J.T1){
      // K half -> kp row-major (tile fully in K range)
      #pragma unroll
      for (int ni=0;ni<4;ni++){
        int c = n0 + wn*64 + ni*16 + l15;
        #pragma unroll
        for (int mi=0;mi<4;mi++){
          int mr0 = m0 + wm*64 + mi*16 + lg*4;
          #pragma unroll
          for (int r4=0;r4<4;r4++)
            J.outb[(size_t)(mr0+r4)*J.T1 + c] = f2bf(acc[mi][ni][r4] + bv[ni]);
        }
      }
    } else {
      // V half -> vpT[(bidx*512 + f)*vstride + key]; coalesce via per-wave
      // LDS transpose (reuse dead As/Bs; 8KB/wave; swizzle ^(f&7)<<4).
      __syncthreads();   // all k-loop LDS reads complete before scratch reuse
      char* scr = (char*)(smem + (wm*2 + wn)*4096);
      #pragma unroll
      for (int ni=0;ni<4;ni++){
        int f_loc = ni*16 + l15;
        #pragma unroll
        for (int mi=0;mi<4;mi++){
          int kb = mi*32 + lg*8;     // key byte offset within 128B row
          uint2 o;
          o.x = (u32)f2bf(acc[mi][ni][0]+bv[ni]) | ((u32)f2bf(acc[mi][ni][1]+bv[ni])<<16);
          o.y = (u32)f2bf(acc[mi][ni][2]+bv[ni]) | ((u32)f2bf(acc[mi][ni][3]+bv[ni])<<16);
          *(uint2*)(scr + f_loc*128 + (kb ^ ((f_loc&7)<<4))) = o;
        }
      }
      int lane = lg*16 + l15;
      int m_base = m0 + wm*64;
      int bidx = m_base >> 12;
      int key0 = m_base & 4095;
      int kc = lane & 7;
      #pragma unroll
      for (int it=0; it<8; it++){
        int f_loc = it*8 + (lane >> 3);
        uint4 v = *(const uint4*)(scr + f_loc*128 + ((kc<<4) ^ ((f_loc&7)<<4)));
        int fg = (n0 - J.T1) + wn*64 + f_loc;
        *(uint4*)(J.out2 + ((size_t)bidx*512 + fg)*(size_t)J.vstride + key0 + kc*8) = v;
      }
    }
  } else if (EPI == 4){
    #pragma unroll
    for (int mi=0;mi<4;mi++){
      #pragma unroll
      for (int r4=0;r4<4;r4++){
        int m = m0 + wm*64 + mi*16 + lg*4 + r4;
        if (m >= J.M) continue;
        float rb = J.bias[m];
        #pragma unroll
        for (int ni=0;ni<4;ni++){
          int c = n0 + wn*64 + ni*16 + l15;
          J.outb[(size_t)m*J.N + c] = f2bf(acc[mi][ni][r4] + rb);
        }
      }
    }
  } else if (EPI == 5){
    float* po_ = J.outf + (size_t)ksp*J.M*J.N;
    #pragma unroll
    for (int mi=0;mi<4;mi++){
      #pragma unroll
      for (int r4=0;r4<4;r4++){
        int m = m0 + wm*64 + mi*16 + lg*4 + r4;
        if (m >= J.M) continue;
        #pragma unroll
        for (int ni=0;ni<4;ni++){
          int c = n0 + wn*64 + ni*16 + l15;
          po_[(size_t)m*J.N + c] = acc[mi][ni][r4];
        }
      }
    }
  } else {
    float bv[4], scl[4];
    #pragma unroll
    for (int ni=0;ni<4;ni++){
      int c = n0 + wn*64 + ni*16 + l15;
      bv[ni]  = J.bias[c];
      scl[ni] = (c < J.scale_cols) ? QSCALE : 1.0f;
    }
    #pragma unroll
    for (int mi=0;mi<4;mi++){
      #pragma unroll
      for (int r4=0;r4<4;r4++){
        int m = m0 + wm*64 + mi*16 + lg*4 + r4;
        if (m >= J.M) continue;
        #pragma unroll
        for (int ni=0;ni<4;ni++){
          int c = n0 + wn*64 + ni*16 + l15;
          float v = acc[mi][ni][r4] + bv[ni];
          if (EPI == 0){
            J.outb[(size_t)m*J.N + c] = f2bf(v*scl[ni]);
          } else if (EPI == 1){
            J.outb[(size_t)m*J.N + c] = f2bf(fmaxf(v, 0.0f));
          } else {
            J.outf[(size_t)m*J.N + c] = v + J.res[(size_t)m*J.N + c];
          }
        }
      }
    }
  }
}

template<int EPI>
__device__ __forceinline__ void gemm_block(const GemmJob& J, int bidIn, u16* smem){
  u16* As = smem;
  u16* Bs = smem + 8192;
  int bid = bidIn;
  int ksp = 0;
  if (J.ksplit > 1){ ksp = bid / J.nblk; bid = bid % J.nblk; }
  if (J.swz){ int cpx = J.nblk >> 3; bid = (bid & 7)*cpx + (bid >> 3); }
  int NT = J.N >> 7;
  int mt = bid / NT, nt = bid % NT;
  int m0 = mt << 7, n0 = nt << 7;
  int kofs = J.k0 + ksp * J.K;
  int tid = threadIdx.x;
  int wid = tid >> 6, lane = tid & 63;
  int wm = wid >> 1, wn = wid & 1;
  int lg = lane >> 4, l15 = lane & 15;

  f32x4 acc[4][4] = {};
  int ktiles = J.K >> 6;
  for (int kt = 0; kt < ktiles; ++kt){
    int k0 = kofs + (kt << 6);
    if (kt) __syncthreads();
    #pragma unroll
    for (int i=0;i<4;i++){
      int L = i*4096 + tid*16;
      int T = L ^ (((L>>7)&7)<<4);
      int row = T >> 7, colb = T & 127;
      int ga = m0 + row; if (ga > J.M-1) ga = J.M-1;
      gl_lds16((const char*)J.A + ((size_t)ga*J.lda + k0)*2 + colb, (char*)As + L);
    }
    #pragma unroll
    for (int i=0;i<4;i++){
      int L = i*4096 + tid*16;
      int T = L ^ (((L>>7)&7)<<4);
      int row = T >> 7, colb = T & 127;
      int rowg = n0 + row;
      if (J.brmap){ int rb = rowg & 127; rowg = (rowg>>7)*J.brmap + (rb < J.brmap ? rb : J.brmap-1); }
      gl_lds16((const char*)J.Bt + ((size_t)rowg*J.lda + k0)*2 + colb, (char*)Bs + L);
    }
    __syncthreads();
    #pragma unroll
    for (int ks=0; ks<2; ++ks){
      bf16x8 af[4], bfr[4];
      #pragma unroll
      for (int mi=0; mi<4; ++mi){
        int r = wm*64 + mi*16 + l15;
        int byt = r*128 + ks*64 + lg*16;
        af[mi] = *(const bf16x8*)((const char*)As + (byt ^ ((r&7)<<4)));
      }
      #pragma unroll
      for (int ni=0; ni<4; ++ni){
        int r = wn*64 + ni*16 + l15;
        int byt = r*128 + ks*64 + lg*16;
        bfr[ni] = *(const bf16x8*)((const char*)Bs + (byt ^ ((r&7)<<4)));
      }
      __builtin_amdgcn_s_setprio(1);
      #pragma unroll
      for (int mi=0;mi<4;mi++)
        #pragma unroll
        for (int ni=0;ni<4;ni++)
          acc[mi][ni] = __builtin_amdgcn_mfma_f32_16x16x32_bf16(af[mi], bfr[ni], acc[mi][ni], 0,0,0);
      __builtin_amdgcn_s_setprio(0);
    }
  }
  epi_store<EPI>(J, acc, m0, n0, wm, wn, lg, l15, ksp, smem);
}

template<int EPIA, int EPIB>
__global__ __launch_bounds__(256) void gemm_multi(GemmJobs G){
  __shared__ __align__(16) u16 smem[16384];
  bool second = (G.njobs > 1) && ((int)blockIdx.x >= G.j[1].blk0);
  if (second) gemm_block<EPIB>(G.j[1], (int)blockIdx.x - G.j[1].blk0, smem);
  else        gemm_block<EPIA>(G.j[0], (int)blockIdx.x, smem);
}

// split-K reduce: out = res + bias[c] + sum_s part[s]; 4 floats per thread
__global__ __launch_bounds__(256) void splitk_reduce(
    const float* __restrict__ part, int nsplit, const float* __restrict__ bias,
    const float* __restrict__ res, float* __restrict__ out, int N, int total4)
{
  int idx = (blockIdx.x*256 + threadIdx.x);
  if (idx >= total4) return;
  int e0 = idx*4;
  size_t MN = (size_t)total4*4;
  float4 a = *(const float4*)(part + e0);
  #pragma unroll
  for (int s=1;s<4;s++){
    float4 p = *(const float4*)(part + s*MN + e0);
    a.x += p.x; a.y += p.y; a.z += p.z; a.w += p.w;
  }
  float4 r = *(const float4*)(res + e0);
  int c = e0 & (N-1);
  float4 bv = *(const float4*)(bias + c);
  float4 o;
  o.x = a.x + r.x + bv.x; o.y = a.y + r.y + bv.y;
  o.z = a.z + r.z + bv.z; o.w = a.w + r.w + bv.w;
  *(float4*)(out + e0) = o;
}

// ---------------- flash attention: 64-key tiles, 2-buf counted-vmcnt pipe ---
template<bool PARTIAL, bool HASMASK, int NTILES>
__global__ __launch_bounds__(256) void attn_kernel(
    const u16* __restrict__ Qp, int ldq,
    const u16* __restrict__ Kp, int ldk, int kcol0,
    const u16* __restrict__ VT, size_t vbs, int vfs,
    const u32* __restrict__ maskw,
    float* __restrict__ pm, float* __restrict__ pl, u16* __restrict__ po,
    u16* __restrict__ o_out,
    int nq, int mk, int S, int H, int Bp, int swz)
{
  __shared__ __align__(16) u16 Ks[2*4096];
  __shared__ __align__(16) u16 Vs[2*4096];
  int bid = blockIdx.x;
  if (swz){ int cpx = gridDim.x >> 3; bid = (bid & 7)*cpx + (bid >> 3); }
  int s = bid % S; int h = (bid / S) % H; int b = bid / (S*H);
  int tid = threadIdx.x, wid = tid>>6, lane = tid&63;
  int lg = lane>>4, l15 = lane&15;
  int qbase = b*nq;
  int kps = mk / S;
  int kbeg = s * kps;
  int mwld = mk >> 5;
  int krel = lg*4;

  bf16x8 qf[2][2];
  #pragma unroll
  for (int mt=0;mt<2;mt++){
    int qr = wid*32 + mt*16 + l15; int qc = qr < nq ? qr : nq-1;
    #pragma unroll
    for (int ks=0;ks<2;ks++)
      qf[mt][ks] = *(const bf16x8*)(Qp + (size_t)(qbase+qc)*ldq + h*64 + ks*32 + lg*8);
  }
  u32 wmw[2][2*NTILES];
  if (HASMASK){
    #pragma unroll
    for (int mt=0;mt<2;mt++){
      int qc = (wid*32 + mt*16 + l15) < nq ? (wid*32 + mt*16 + l15) : nq-1;
      const u32* mrow = maskw + (size_t)(qbase+qc)*mwld + (kbeg>>5);
      #pragma unroll
      for (int wi=0; wi<2*NTILES; wi+=4){
        uint4 v = *(const uint4*)(mrow + wi);
        wmw[mt][wi+0]=v.x; wmw[mt][wi+1]=v.y; wmw[mt][wi+2]=v.z; wmw[mt][wi+3]=v.w;
      }
    }
  }

  float m_r[2] = {NEG_INF, NEG_INF};
  float l_r[2] = {0.0f, 0.0f};
  f32x4 of[2][4] = {};

  auto stage = [&](int t_, int bufi){
    int kb_ = kbeg + t_*64;
    #pragma unroll
    for (int i=0;i<2;i++){
      int idx = i*256 + tid;
      int key = idx>>3, sd = idx&7;
      int kc = kb_ + key; if (kc > mk-1) kc = mk-1;
      const char* src = (const char*)(Kp + (size_t)(b*mk + kc)*ldk + kcol0 + h*64) + ((sd ^ (key&7))<<4);
      gl_lds16(src, (char*)Ks + bufi*8192 + idx*16);
    }
    #pragma unroll
    for (int i=0;i<2;i++){
      int idx = i*256 + tid;
      int f = idx>>3, sd = idx&7;
      const char* src = (const char*)(VT + (size_t)b*vbs + (size_t)(h*64+f)*vfs + kb_) + ((sd ^ (f&7))<<4);
      gl_lds16(src, (char*)Vs + bufi*8192 + idx*16);
    }
  };

  stage(0, 0);

  #pragma unroll
  for (int t=0;t<NTILES;t++){
    if (t+1 < NTILES){
      stage(t+1, (t+1)&1);
      asm volatile("s_waitcnt vmcnt(4)" ::: "memory");
    } else {
      asm volatile("s_waitcnt vmcnt(0)" ::: "memory");
    }
    __builtin_amdgcn_s_barrier();

    const char* Kb = (const char*)Ks + (t&1)*8192;
    const char* Vb = (const char*)Vs + (t&1)*8192;
    int kb = kbeg + t*64;

    f32x4 sT[4][2] = {};
    #pragma unroll
    for (int nt2=0;nt2<4;nt2++){
      bf16x8 k0 = *(const bf16x8*)(Kb + ((nt2*16+l15)<<7) + (((lg  ) ^ (l15&7))<<4));
      bf16x8 k1 = *(const bf16x8*)(Kb + ((nt2*16+l15)<<7) + (((4+lg) ^ (l15&7))<<4));
      __builtin_amdgcn_s_setprio(1);
      #pragma unroll
      for (int mt=0;mt<2;mt++){
        sT[nt2][mt] = __builtin_amdgcn_mfma_f32_16x16x32_bf16(k0, qf[mt][0], sT[nt2][mt], 0,0,0);
        sT[nt2][mt] = __builtin_amdgcn_mfma_f32_16x16x32_bf16(k1, qf[mt][1], sT[nt2][mt], 0,0,0);
      }
      __builtin_amdgcn_s_setprio(0);
    }

    s16x4 pb[2][4];
    #pragma unroll
    for (int mt=0;mt<2;mt++){
      float mx = NEG_INF;
      #pragma unroll
      for (int nt2=0;nt2<4;nt2++){
        u32 wb = 0;
        if (HASMASK) wb = wmw[mt][t*2 + (nt2>>1)] >> (((nt2&1)<<4) + krel);
        #pragma unroll
        for (int r=0;r<4;r++){
          bool ok = HASMASK ? (((wb>>r)&1u) != 0) : (kb + nt2*16 + krel + r < mk);
          float sv = ok ? sT[nt2][mt][r] : NEG_INF;
          sT[nt2][mt][r] = sv;
          mx = fmaxf(mx, sv);
        }
      }
      mx = fmaxf(mx, __shfl_xor(mx, 16, 64));
      mx = fmaxf(mx, __shfl_xor(mx, 32, 64));
      if (!__all(mx <= m_r[mt] + 8.0f)){
        float mnew = fmaxf(m_r[mt], mx);
        float corr = exp2f(m_r[mt] - mnew);
        m_r[mt] = mnew;
        l_r[mt] *= corr;
        #pragma unroll
        for (int nf=0;nf<4;nf++) of[mt][nf] *= corr;
      }
      float ps = 0.0f;
      #pragma unroll
      for (int nt2=0;nt2<4;nt2++)
        #pragma unroll
        for (int r=0;r<4;r++){
          float p = exp2f(sT[nt2][mt][r] - m_r[mt]);
          ps += p;
          pb[mt][nt2][r] = f2bf_s(p);
        }
      ps += __shfl_xor(ps, 16, 64);
      ps += __shfl_xor(ps, 32, 64);
      l_r[mt] += ps;
    }

    #pragma unroll
    for (int nf=0;nf<4;nf++){
      s16x4 vf[4];
      #pragma unroll
      for (int nt2=0;nt2<4;nt2++){
        int slot = (nt2*2 + (lg>>1)) ^ (l15&7);
        vf[nt2] = *(const s16x4*)(Vb + ((nf*16+l15)<<7) + (slot<<4) + ((lg&1)<<3));
      }
      __builtin_amdgcn_s_setprio(1);
      #pragma unroll
      for (int mt=0;mt<2;mt++)
        #pragma unroll
        for (int nt2=0;nt2<4;nt2++)
          of[mt][nf] = mfma16(vf[nt2], pb[mt][nt2], of[mt][nf]);
      __builtin_amdgcn_s_setprio(0);
    }
    __builtin_amdgcn_s_barrier();
  }

  #pragma unroll
  for (int mt=0;mt<2;mt++){
    int q = wid*32 + mt*16 + l15;
    if (q < nq){
      if (PARTIAL){
        size_t base = (((size_t)(s*Bp + b)*H + h)*128 + q);
        if (lg == 0){ pm[base] = m_r[mt]; pl[base] = l_r[mt]; }
        #pragma unroll
        for (int nf=0;nf<4;nf++){
          uint2 o;
          o.x = (u32)f2bf(of[mt][nf][0]) | ((u32)f2bf(of[mt][nf][1])<<16);
          o.y = (u32)f2bf(of[mt][nf][2]) | ((u32)f2bf(of[mt][nf][3])<<16);
          *(uint2*)(po + base*64 + nf*16 + lg*4) = o;
        }
      } else {
        float inv = 1.0f / l_r[mt];
        #pragma unroll
        for (int nf=0;nf<4;nf++){
          uint2 o;
          o.x = (u32)f2bf(of[mt][nf][0]*inv) | ((u32)f2bf(of[mt][nf][1]*inv)<<16);
          o.y = (u32)f2bf(of[mt][nf][2]*inv) | ((u32)f2bf(of[mt][nf][3]*inv)<<16);
          *(uint2*)(o_out + (size_t)(qbase+q)*512 + h*64 + nf*16 + lg*4) = o;
        }
      }
    }
  }
}

__global__ __launch_bounds__(64) void attn_combine(
    const float* __restrict__ pm, const float* __restrict__ pl, const u16* __restrict__ po,
    u16* __restrict__ o_out, int S, int Bp, int H, int nq)
{
  int bid = blockIdx.x;
  int q = bid % nq; int h = (bid / nq) % H; int b = bid / (nq*H);
  int f = threadIdx.x;
  float mstar = NEG_INF;
  for (int s=0;s<S;s++){
    size_t idx = (((size_t)(s*Bp + b)*H + h)*128 + q);
    mstar = fmaxf(mstar, pm[idx]);
  }
  float L = 0.0f, acc = 0.0f;
  for (int s=0;s<S;s++){
    size_t idx = (((size_t)(s*Bp + b)*H + h)*128 + q);
    float w = exp2f(pm[idx] - mstar);
    L += w * pl[idx];
    acc += w * bf2f(po[idx*64 + f]);
  }
  o_out[((size_t)b*nq + q)*512 + h*64 + f] = f2bf(acc / L);
}

// ---------------------------------------------------------------------------
extern "C" void kernel_launch(void* const* d_in, const int* in_sizes, int n_in,
                              void* d_out, int out_size, void* d_ws, size_t ws_size,
                              hipStream_t stream){
  const float* q_in    = (const float*)d_in[0];
  const float* kv_in   = (const float*)d_in[1];
  const int*   maskb   = (const int*)d_in[2];
  const float* xa_Wqkv = (const float*)d_in[3];
  const float* xa_bqkv = (const float*)d_in[4];
  const float* xa_Wo   = (const float*)d_in[5];
  const float* xa_bo   = (const float*)d_in[6];
  const float* xa_gq   = (const float*)d_in[7];
  const float* xa_bq   = (const float*)d_in[8];
  const float* xa_gkv  = (const float*)d_in[9];
  const float* xa_bkv  = (const float*)d_in[10];
  const float* sa_Wqkv = (const float*)d_in[11];
  const float* sa_bqkv = (const float*)d_in[12];
  const float* sa_Wo   = (const float*)d_in[13];
  const float* sa_bo   = (const float*)d_in[14];
  const float* n1_g = (const float*)d_in[15];
  const float* n1_b = (const float*)d_in[16];
  const float* n2_g = (const float*)d_in[17];
  const float* n2_b = (const float*)d_in[18];
  const float* ff_W1 = (const float*)d_in[19];
  const float* ff_b1 = (const float*)d_in[20];
  const float* ff_W2 = (const float*)d_in[21];
  const float* ff_b2 = (const float*)d_in[22];

  char* ws = (char*)d_ws;
  size_t off = 0;
  auto alloc = [&](size_t bytes)->char*{ char* p = ws + off; off = (off + bytes + 255) & ~(size_t)255; return p; };
  u16* wq  = (u16*)alloc((size_t)512*512*2);
  u16* wkv = (u16*)alloc((size_t)1024*512*2);
  u16* wsa = (u16*)alloc((size_t)1536*512*2);
  u16* wxo = (u16*)alloc((size_t)512*512*2);
  u16* wso = (u16*)alloc((size_t)512*512*2);
  u16* wf1 = (u16*)alloc((size_t)2048*512*2);
  u16* wf2 = (u16*)alloc((size_t)512*2048*2);
  u16* qn  = (u16*)alloc((size_t)800*512*2);
  u16* qp  = (u16*)alloc((size_t)800*512*2);
  u32* mw  = (u32*)alloc((size_t)800*128*4);
  u16* kp  = (u16*)alloc((size_t)32768*512*2);
  u16* vpT = (u16*)alloc((size_t)8*512*4096*2);   // [(b*512+f)][4096 keys]
  size_t reuse_off = off;
  u16* kvn = (u16*)alloc((size_t)32768*512*2);
  size_t offB = reuse_off;
  auto allocB = [&](size_t bytes)->char*{ char* p = ws + offB; offB = (offB + bytes + 255) & ~(size_t)255; return p; };
  const int S = 16;
  float* pm   = (float*)allocB((size_t)S*64*128*4);
  float* pl   = (float*)allocB((size_t)S*64*128*4);
  u16*   po   = (u16*)allocB((size_t)S*64*128*64*2);
  u16* o_xa   = (u16*)allocB((size_t)800*512*2);
  float* x1   = (float*)allocB((size_t)800*512*4);
  u16* qn1    = (u16*)allocB((size_t)800*512*2);
  u16* saqkv  = (u16*)allocB((size_t)800*1024*2);
  u16* vT2sa  = (u16*)allocB((size_t)512*1024*2);
  u16* o_sa   = (u16*)allocB((size_t)800*512*2);
  float* x2   = (float*)allocB((size_t)800*512*4);
  u16* qn2    = (u16*)allocB((size_t)800*512*2);
  u16* hbuf   = (u16*)allocB((size_t)800*2048*2);
  // split-K partials (FFN2): 4 x 800x512 fp32; alias dead pm/pl/po region
  float* fpart = pm;

  // ---- single prep dispatch: 7 wtrans jobs + LN(q) + LN(kv) + mask --------
  PrepArgs P;
  P.wt.W[0]=xa_Wqkv; P.wt.Wt[0]=wq;  P.wt.K[0]=512;  P.wt.Nfull[0]=1536; P.wt.ncol0[0]=0;   P.wt.nt[0]=16;
  P.wt.W[1]=xa_Wqkv; P.wt.Wt[1]=wkv; P.wt.K[1]=512;  P.wt.Nfull[1]=1536; P.wt.ncol0[1]=512; P.wt.nt[1]=32;
  P.wt.W[2]=sa_Wqkv; P.wt.Wt[2]=wsa; P.wt.K[2]=512;  P.wt.Nfull[2]=1536; P.wt.ncol0[2]=0;   P.wt.nt[2]=48;
  P.wt.W[3]=xa_Wo;   P.wt.Wt[3]=wxo; P.wt.K[3]=512;  P.wt.Nfull[3]=512;  P.wt.ncol0[3]=0;   P.wt.nt[3]=16;
  P.wt.W[4]=sa_Wo;   P.wt.Wt[4]=wso; P.wt.K[4]=512;  P.wt.Nfull[4]=512;  P.wt.ncol0[4]=0;   P.wt.nt[4]=16;
  P.wt.W[5]=ff_W1;   P.wt.Wt[5]=wf1; P.wt.K[5]=512;  P.wt.Nfull[5]=2048; P.wt.ncol0[5]=0;   P.wt.nt[5]=64;
  P.wt.W[6]=ff_W2;   P.wt.Wt[6]=wf2; P.wt.K[6]=2048; P.wt.Nfull[6]=512;  P.wt.ncol0[6]=0;   P.wt.nt[6]=16;
  int tot = 0;
  for (int i=0;i<7;i++){ P.wt.blk0[i] = tot; tot += (P.wt.K[i]/32)*P.wt.nt[i]; }
  P.totW = tot;
  P.x0=q_in;  P.g0=xa_gq;  P.b0=xa_bq;  P.o0=qn;  P.nb0=200;  P.rows0=800;
  P.x1=kv_in; P.g1=xa_gkv; P.b1=xa_bkv; P.o1=kvn; P.nb1=8192; P.rows1=32768;
  P.mask=maskb; P.mw=mw;
  prep_all<<<tot + 200 + 8192 + 400, 256, 0, stream>>>(P);

  auto mkjob = [&](const u16*A, const u16*Bt, const float*bias, float*outf, u16*outb,
                   const float*res, u16*out2, int M, int N, int K, int lda, int k0,
                   int ksplit, int sc, int T1, int rpb, int vst, int swz, int brm,
                   int blk0, int nblk)->GemmJob{
    GemmJob j; j.A=A; j.Bt=Bt; j.bias=bias; j.outf=outf; j.outb=outb; j.res=res; j.out2=out2;
    j.M=M; j.N=N; j.K=K; j.lda=lda; j.k0=k0; j.ksplit=ksplit; j.scale_cols=sc; j.T1=T1;
    j.rows_per_b=rpb; j.vstride=vst; j.swz=swz; j.brmap=brm; j.blk0=blk0; j.nblk=nblk;
    return j;
  };

  // Q projection (QSCALE folded) || fused K,V projection (K row-major + V^T)
  {
    GemmJobs g;
    g.j[0] = mkjob(qn, wq, xa_bqkv, nullptr, qp, nullptr, nullptr,
                   800, 512, 512, 512, 0, 1, 512, 0,1,1, 0,0, 0, 28);
    g.j[1] = mkjob(kvn, wkv, xa_bqkv+512, nullptr, kp, nullptr, vpT,
                   32768, 1024, 512, 512, 0, 1, 0, 512, 4096, 4096, 1, 0, 28, 2048);
    g.njobs = 2;
    gemm_multi<0,3><<<28 + 2048, 256, 0, stream>>>(g);
  }
  attn_kernel<true,true,4><<<8*8*S, 256, 0, stream>>>(
      qp, 512, kp, 512, 0, vpT, (size_t)512*4096, 4096, mw,
      pm, pl, po, nullptr, 100, 4096, S, 8, 8, 1);
  attn_combine<<<8*8*100, 64, 0, stream>>>(pm, pl, po, o_xa, S, 8, 8, 100);
  {
    GemmJobs g;
    g.j[0] = mkjob(o_xa, wxo, xa_bo, x1, nullptr, q_in, nullptr,
                   800, 512, 512, 512, 0, 1, 0, 0,1,1, 0,0, 0, 28);
    g.j[1] = g.j[0]; g.njobs = 1;
    gemm_multi<2,2><<<28, 256, 0, stream>>>(g);
  }
  ln_rows<<<200, 256, 0, stream>>>(x1, n1_g, n1_b, qn1, 800);
  {
    GemmJobs g;
    g.j[0] = mkjob(qn1, wsa, sa_bqkv, nullptr, saqkv, nullptr, nullptr,
                   800, 1024, 512, 512, 0, 1, 512, 0,1,1, 0,0, 0, 56);
    g.j[1] = mkjob(wsa + (size_t)1024*512, qn1, sa_bqkv+1024, nullptr, vT2sa, nullptr, nullptr,
                   512, 1024, 512, 512, 0, 1, 0, 0,1,1, 0, 100, 56, 32);
    g.njobs = 2;
    gemm_multi<0,4><<<56 + 32, 256, 0, stream>>>(g);
  }
  attn_kernel<false,false,2><<<64, 256, 0, stream>>>(
      saqkv, 1024, saqkv, 1024, 512, vT2sa, (size_t)128, 1024, nullptr,
      nullptr, nullptr, nullptr, o_sa, 100, 100, 1, 8, 8, 0);
  {
    GemmJobs g;
    g.j[0] = mkjob(o_sa, wso, sa_bo, x2, nullptr, x1, nullptr,
                   800, 512, 512, 512, 0, 1, 0, 0,1,1, 0,0, 0, 28);
    g.j[1] = g.j[0]; g.njobs = 1;
    gemm_multi<2,2><<<28, 256, 0, stream>>>(g);
  }
  ln_rows<<<200, 256, 0, stream>>>(x2, n2_g, n2_b, qn2, 800);
  {
    GemmJobs g;
    g.j[0] = mkjob(qn2, wf1, ff_b1, nullptr, hbuf, nullptr, nullptr,
                   800, 2048, 512, 512, 0, 1, 0, 0,1,1, 0,0, 0, 112);
    g.j[1] = g.j[0]; g.njobs = 1;
    gemm_multi<1,1><<<112, 256, 0, stream>>>(g);
  }
  // FFN2: split-K x4 (K=2048 -> 4x512), fp32 partials into dead attn scratch
  {
    GemmJobs g;
    g.j[0] = mkjob(hbuf, wf2, nullptr, fpart, nullptr, nullptr, nullptr,
                   800, 512, 512, 2048, 0, 4, 0, 0,1,1, 0,0, 0, 28);
    g.j[1] = g.j[0]; g.njobs = 1;
    gemm_multi<5,5><<<112, 256, 0, stream>>>(g);
  }
  splitk_reduce<<<(800*512/4 + 255)/256, 256, 0, stream>>>(
      fpart, 4, ff_b2, x2, (float*)d_out, 512, 800*512/4);
}